// Round 7
// baseline (661.850 us; speedup 1.0000x reference)
//
#include <hip/hip_runtime.h>

#define B_   8192
#define K_   5
#define D_   128
#define QD_  129
#define KD_  1285
#define SQ_  132      // padded fp32 row stride
#define BK_  40960    // B_*K_
#define QPAD 160      // bf16 k-dim padding (5 x 32)
#define VPAD 144      // bf16 out-dim padding (9 x 16)
#define KDP  1312     // KD_ padded to 41*32

typedef unsigned short u16;
typedef unsigned int   u32;
typedef __attribute__((ext_vector_type(8))) short bf8_t;
typedef __attribute__((ext_vector_type(4))) float f4_t;
typedef __attribute__((address_space(3))) u32 lds_u32;
typedef __attribute__((address_space(1))) const u32 glob_u32;

#define MFMA16(a, b, c) __builtin_amdgcn_mfma_f32_16x16x32_bf16(a, b, c, 0, 0, 0)

__device__ __forceinline__ u16 f2bf(float x) {
  u32 u = __float_as_uint(x);
  u = (u + 0x7fffu + ((u >> 16) & 1u)) >> 16;
  return (u16)u;
}
__device__ __forceinline__ u32 pack2(float a, float b) {
  return (u32)f2bf(a) | ((u32)f2bf(b) << 16);
}
// LDS W layout: row stride 32 u16 (64B), 8-u16 sub-blocks XOR-swizzled by row.
__device__ __forceinline__ int swz8(int row, int seg) {
  return (row << 5) + (((seg ^ (row >> 1)) & 3) << 3);
}
__device__ __forceinline__ void gload16(const u16* src, u16* ldsdst) {
  __builtin_amdgcn_global_load_lds((glob_u32*)src, (lds_u32*)ldsdst, 16, 0, 0);
}
#define WAIT_VM0() asm volatile("s_waitcnt vmcnt(0)" ::: "memory")

// ---------------------------------------------------------------------------
// One-time weight conversion fp32 -> bf16 with zero padding.
//   wkv [288][1312] @0        rows 0-128 Wk, 129-257 Wv
//   wq  [144][160]  @377856
//   wo  [144][160]  @400896
//   w1  [144][288]  @423936
//   w2  [144][128]  @465408
// ---------------------------------------------------------------------------
__global__ __launch_bounds__(256) void convw_k(
    const float* __restrict__ Wq, const float* __restrict__ Wk,
    const float* __restrict__ Wv, const float* __restrict__ Wo,
    const float* __restrict__ W1, const float* __restrict__ W2,
    u16* __restrict__ wb)
{
  int idx = blockIdx.x * 256 + threadIdx.x;
  if (idx < 377856) {
    int r = idx / KDP, c = idx - r * KDP;
    float v = 0.f;
    if (c < KD_) {
      if (r < 129) v = Wk[r * KD_ + c];
      else if (r < 258) v = Wv[(r - 129) * KD_ + c];
    }
    wb[idx] = f2bf(v);
    return;
  }
  int i2 = idx - 377856;
  if (i2 < 23040) {
    int r = i2 / 160, c = i2 - r * 160;
    wb[idx] = f2bf((r < 129 && c < 129) ? Wq[r * 129 + c] : 0.f);
    return;
  }
  i2 -= 23040;
  if (i2 < 23040) {
    int r = i2 / 160, c = i2 - r * 160;
    wb[idx] = f2bf((r < 129 && c < 129) ? Wo[r * 129 + c] : 0.f);
    return;
  }
  i2 -= 23040;
  if (i2 < 41472) {
    int r = i2 / 288, c = i2 - r * 288;
    wb[idx] = f2bf((r < 128 && c < 257) ? W1[r * 257 + c] : 0.f);
    return;
  }
  i2 -= 41472;
  if (i2 < 18432) {
    int r = i2 / 128, c = i2 - r * 128;
    wb[idx] = f2bf(r < 128 ? W2[r * 128 + c] : 0.f);
  }
}

// ---------------------------------------------------------------------------
// Unified bf16 MFMA GEMM. BM=64 rows, BN=144 cols per block, 256 thr,
// 4 waves as 4Mx1N (wave: 16 rows x 144 cols, 9 MFMA/step).
// A operand DIRECT TO REGISTERS (no LDS):
//   GA=0: A bf16 row-major, 1 bf8 load/lane/step.
//   GA=1: A=[emb f32 [n][128] | td | 0], 8 f32 gather + cvt.
//   GA=2: A=nf gather (emb,ef,td fused concat), 8 f32 gather + cvt.
// W staged in LDS via global_load_lds (pre-swizzled source), double-buffered.
// nch column-halves (nch=2 splits N=288 across block pairs sharing A rows).
// Epilogue col = colh*144 + ct*16 + lrow: col<N0 -> out0, else DUAL -> out1.
// OM: 0=f32 row-major, 1=bf16 row-major, 2=bf16 transposed.
// ---------------------------------------------------------------------------
template<int GA, bool RELU, int OM0, int OM1, bool DUAL>
__global__ __launch_bounds__(256) void gmm_k(
    int nK, int Kw, int nch,
    const void* __restrict__ A, int ast,
    const float* __restrict__ g1, const float* __restrict__ g2,
    const u16* __restrict__ Wb,
    const float* __restrict__ b0, void* __restrict__ out0, int ost0, int N0,
    const float* __restrict__ b1, void* __restrict__ out1, int ost1,
    float scale)
{
  __shared__ u16 Ws_[2][9 * 512];
  const int t = threadIdx.x, lane = t & 63, w = t >> 6;
  const int lrow = lane & 15, lk = lane >> 4;
  const int bid = blockIdx.x;
  const int x = bid / nch, colh = bid - x * nch;
  const int n0 = x * 64;
  const int colofs = colh * 144;
  const int drow = lane >> 2, dseg = lane & 3;
  const int arow = n0 + w * 16 + lrow;

  f4_t acc[9];
#pragma unroll
  for (int ct = 0; ct < 9; ++ct) acc[ct] = (f4_t){0.f, 0.f, 0.f, 0.f};

  bf8_t afE, afO;
  float rE[8], rO[8];

  auto issueR = [&](int kst, float (&r)[8]) {
    const int cb = kst * 32 + lk * 8;
#pragma unroll
    for (int i = 0; i < 8; ++i) {
      int c = cb + i;
      if (GA == 1) {
        uintptr_t pa = (uintptr_t)((const float*)A + (arow << 7) + c);
        uintptr_t pt = (uintptr_t)(g2 ? (g2 + arow) : (const float*)A);
        uintptr_t sel = (c < 128) ? pa : pt;
        float v = *(const float*)sel;
        r[i] = (c < 128) ? v : ((c == 128 && g2) ? v : 0.f);
      } else {
        int j = c / 257;
        int rr = c - j * 257;
        int base = (arow * 5 + j) << 7;
        uintptr_t pe = (uintptr_t)((const float*)A + base + rr);
        uintptr_t pf = (uintptr_t)(g1 + base + (rr - 128));
        uintptr_t pt = (uintptr_t)(g2 + arow * 5 + j);
        uintptr_t sel = (rr < 128) ? pe : (rr < 256) ? pf : pt;
        if (j >= 5) sel = (uintptr_t)g2;
        float v = *(const float*)sel;
        r[i] = (j < 5) ? v : 0.f;
      }
    }
  };
  auto cvt8 = [&](const float (&r)[8]) -> bf8_t {
    union { bf8_t v; u32 u[4]; } xx;
#pragma unroll
    for (int i = 0; i < 4; ++i) xx.u[i] = pack2(r[2 * i], r[2 * i + 1]);
    return xx.v;
  };
  auto loadAf = [&](int kst) -> bf8_t {
    return *(const bf8_t*)((const u16*)A + (size_t)arow * ast + kst * 32 + lk * 8);
  };
  auto dmaW = [&](int kst, u16* wbuf) {
    const int c0 = kst * 32;
#pragma unroll
    for (int si = 0; si < 3; ++si) {
      int s = w + si * 4;            // wave-uniform
      if (s < 9) {
        int rr = colofs + s * 16 + drow;
        int sseg = (dseg ^ (rr >> 1)) & 3;
        gload16(&Wb[(size_t)rr * Kw + c0 + sseg * 8], wbuf + s * 512);
      }
    }
  };
  auto compute = [&](bf8_t af, const u16* wsb) {
#pragma unroll
    for (int ct = 0; ct < 9; ++ct) {
      bf8_t bf = *(const bf8_t*)&wsb[swz8(ct * 16 + lrow, lk)];
      acc[ct] = MFMA16(af, bf, acc[ct]);
    }
  };

  // prologue: tile 0
  if (GA == 0) afE = loadAf(0); else issueR(0, rE);
  dmaW(0, Ws_[0]);
  WAIT_VM0();
  if (GA != 0) afE = cvt8(rE);
  __builtin_amdgcn_s_barrier();

  int cur = 0, k = 0;
  while (true) {
    // even-slot step (uses afE)
    if (k + 1 < nK) {
      if (GA == 0) afO = loadAf(k + 1); else issueR(k + 1, rO);
      dmaW(k + 1, Ws_[cur ^ 1]);
    }
    compute(afE, Ws_[cur]);
    if (k + 1 >= nK) break;
    WAIT_VM0();
    if (GA != 0) afO = cvt8(rO);
    __builtin_amdgcn_s_barrier();
    cur ^= 1; ++k;
    // odd-slot step (uses afO)
    if (k + 1 < nK) {
      if (GA == 0) afE = loadAf(k + 1); else issueR(k + 1, rE);
      dmaW(k + 1, Ws_[cur ^ 1]);
    }
    compute(afO, Ws_[cur]);
    if (k + 1 >= nK) break;
    WAIT_VM0();
    if (GA != 0) afE = cvt8(rE);
    __builtin_amdgcn_s_barrier();
    cur ^= 1; ++k;
  }

  // epilogue
#pragma unroll
  for (int ct = 0; ct < 9; ++ct) {
    const int col = colofs + ct * 16 + lrow;
#pragma unroll
    for (int r = 0; r < 4; ++r) {
      const int n = n0 + w * 16 + lk * 4 + r;
      float v = acc[ct][r];
      if (col < N0) {
        v = (v + b0[col]) * scale;
        if (RELU) v = fmaxf(v, 0.f);
        if (OM0 == 0)      ((float*)out0)[(size_t)n * ost0 + col] = v;
        else if (OM0 == 1) ((u16*)out0)[(size_t)n * ost0 + col] = f2bf(v);
        else               ((u16*)out0)[(size_t)col * ost0 + n] = f2bf(v);
      } else if (DUAL) {
        int o = col - N0;
        if (o < 129) {
          v = (v + b1[o]) * scale;
          if (RELU) v = fmaxf(v, 0.f);
          if (OM1 == 0)      ((float*)out1)[(size_t)n * ost1 + o] = v;
          else if (OM1 == 1) ((u16*)out1)[(size_t)n * ost1 + o] = f2bf(v);
          else               ((u16*)out1)[(size_t)o * ost1 + n] = f2bf(v);
        }
      }
    }
  }
}

// ---------------------------------------------------------------------------
// emb pack: f32 [rows][128] -> bf16 into dst cols 129..256 (stride 288)
// ---------------------------------------------------------------------------
__global__ __launch_bounds__(256) void embpack_k(
    const float* __restrict__ src, u16* __restrict__ dst, int rows)
{
  int idx = blockIdx.x * 256 + threadIdx.x;
  if (idx >= rows * 128) return;
  int n = idx >> 7, c = idx & 127;
  dst[(size_t)n * 288 + 129 + c] = f2bf(src[idx]);
}

// ---------------------------------------------------------------------------
// i=0 attention: per batch b, 5 queries x 5 keys, dim 129.
// ---------------------------------------------------------------------------
__global__ __launch_bounds__(256) void attn0_k(
    const float* __restrict__ qp, const float* __restrict__ kp,
    const float* __restrict__ vp, u16* __restrict__ o0b)
{
  __shared__ float qs[4][5][SQ_], ks[4][5][SQ_], vs[4][5][SQ_];
  __shared__ float ps[4][5][8];
  const int t = threadIdx.x;
  const int bbase = blockIdx.x * 4;
  for (int idx = t; idx < 4 * 5 * SQ_; idx += 256) {
    int bl = idx / (5 * SQ_);
    int rem = idx - bl * 5 * SQ_;
    int row = rem / SQ_;
    int d = rem - row * SQ_;
    int n = (bbase + bl) * 5 + row;
    float qv = 0.f, kv = 0.f, vv = 0.f;
    if (d < QD_) { qv = qp[n * SQ_ + d]; kv = kp[n * SQ_ + d]; vv = vp[n * SQ_ + d]; }
    qs[bl][row][d] = qv; ks[bl][row][d] = kv; vs[bl][row][d] = vv;
  }
  __syncthreads();
  const int w = t >> 6, lane = t & 63;
  if (lane < 25) {
    int qq = lane / 5, kk = lane - (lane / 5) * 5;
    float s = 0.f;
    for (int c = 0; c < QD_; ++c) s += qs[w][qq][c] * ks[w][kk][c];
    ps[w][qq][kk] = s;
  }
  __syncthreads();
  if (lane < 5) {
    float m = -1e30f;
#pragma unroll
    for (int k = 0; k < 5; ++k) m = fmaxf(m, ps[w][lane][k]);
    float l = 0.f; float e[5];
#pragma unroll
    for (int k = 0; k < 5; ++k) { e[k] = __expf(ps[w][lane][k] - m); l += e[k]; }
    float inv = 1.f / l;
#pragma unroll
    for (int k = 0; k < 5; ++k) ps[w][lane][k] = e[k] * inv;
  }
  __syncthreads();
  for (int d = lane; d < 160; d += 64) {
#pragma unroll
    for (int qq = 0; qq < 5; ++qq) {
      float o = 0.f;
      if (d < QD_) {
#pragma unroll
        for (int k = 0; k < 5; ++k) o += ps[w][qq][k] * vs[w][k][d];
      }
      o0b[(size_t)((bbase + w) * 5 + qq) * 160 + d] = f2bf(o);
    }
  }
}

// ---------------------------------------------------------------------------
// i=1 MFMA flash attention (unchanged).
// ---------------------------------------------------------------------------
#define KSS 168
#define VSS 72
#define PSS 72
#define NSPLIT 4
__global__ __launch_bounds__(256) void flashm_k(
    const u16* __restrict__ qp, const u16* __restrict__ kp,
    const u16* __restrict__ vpT, float* __restrict__ oacc,
    float* __restrict__ marr, float* __restrict__ larr)
{
  __shared__ u16 ks[64 * KSS];
  __shared__ u16 vsT[VPAD * VSS];
  __shared__ u16 ps[64 * PSS];
  const int t = threadIdx.x;
  const int split = blockIdx.x & (NSPLIT - 1);
  const int q0 = (blockIdx.x >> 2) * 64;
  const int w = t >> 6, lane = t & 63;
  const int lrow = lane & 15, lk = lane >> 4;

  bf8_t qf[5];
  {
    const u16* qrow = qp + (size_t)(q0 + w * 16 + lrow) * QPAD;
#pragma unroll
    for (int kst = 0; kst < 5; ++kst)
      qf[kst] = *(const bf8_t*)(qrow + kst * 32 + lk * 8);
  }

  f4_t acc[9];
#pragma unroll
  for (int ct = 0; ct < 9; ++ct) acc[ct] = (f4_t){0.f, 0.f, 0.f, 0.f};
  float m_[4] = {-1e30f, -1e30f, -1e30f, -1e30f};
  float l_[4] = {0.f, 0.f, 0.f, 0.f};

  const int kbase = split * (B_ / NSPLIT);
  for (int tile = 0; tile < (B_ / NSPLIT) / 64; ++tile) {
    const int k0 = kbase + tile * 64;
    __syncthreads();
    for (int e = t; e < 64 * 20; e += 256) {
      int r = e / 20, c = e - r * 20;
      *(uint4*)&ks[r * KSS + c * 8] = *(const uint4*)(kp + (size_t)(k0 + r) * QPAD + c * 8);
    }
    for (int e = t; e < VPAD * 8; e += 256) {
      int r = e >> 3, c = e & 7;
      *(uint4*)&vsT[r * VSS + c * 8] = *(const uint4*)(vpT + (size_t)r * B_ + k0 + c * 8);
    }
    __syncthreads();

    f4_t s[4];
#pragma unroll
    for (int ct = 0; ct < 4; ++ct) s[ct] = (f4_t){0.f, 0.f, 0.f, 0.f};
#pragma unroll
    for (int kst = 0; kst < 5; ++kst) {
#pragma unroll
      for (int ct = 0; ct < 4; ++ct) {
        bf8_t b = *(const bf8_t*)&ks[(ct * 16 + lrow) * KSS + kst * 32 + lk * 8];
        s[ct] = MFMA16(qf[kst], b, s[ct]);
      }
    }

    float pm[4];
#pragma unroll
    for (int r = 0; r < 4; ++r) {
      pm[r] = fmaxf(fmaxf(s[0][r], s[1][r]), fmaxf(s[2][r], s[3][r]));
#pragma unroll
      for (int mk = 1; mk <= 8; mk <<= 1) pm[r] = fmaxf(pm[r], __shfl_xor(pm[r], mk));
    }
    float cf[4], rs[4];
#pragma unroll
    for (int r = 0; r < 4; ++r) {
      float mn = fmaxf(m_[r], pm[r]);
      cf[r] = __expf(m_[r] - mn);
      m_[r] = mn;
      rs[r] = 0.f;
    }
#pragma unroll
    for (int ct = 0; ct < 4; ++ct) {
#pragma unroll
      for (int r = 0; r < 4; ++r) {
        float p = __expf(s[ct][r] - m_[r]);
        ps[(w * 16 + lk * 4 + r) * PSS + ct * 16 + lrow] = f2bf(p);
        rs[r] += p;
      }
    }
#pragma unroll
    for (int r = 0; r < 4; ++r) {
#pragma unroll
      for (int mk = 1; mk <= 8; mk <<= 1) rs[r] += __shfl_xor(rs[r], mk);
      l_[r] = l_[r] * cf[r] + rs[r];
    }
#pragma unroll
    for (int ct = 0; ct < 9; ++ct) {
#pragma unroll
      for (int r = 0; r < 4; ++r) acc[ct][r] *= cf[r];
    }
    __syncthreads();

#pragma unroll
    for (int kst = 0; kst < 2; ++kst) {
      bf8_t a = *(const bf8_t*)&ps[(w * 16 + lrow) * PSS + kst * 32 + lk * 8];
#pragma unroll
      for (int ct = 0; ct < 9; ++ct) {
        bf8_t b = *(const bf8_t*)&vsT[(ct * 16 + lrow) * VSS + kst * 32 + lk * 8];
        acc[ct] = MFMA16(a, b, acc[ct]);
      }
    }
  }

#pragma unroll
  for (int ct = 0; ct < 9; ++ct) {
    const int col = ct * 16 + lrow;
    if (col < SQ_) {
#pragma unroll
      for (int r = 0; r < 4; ++r)
        oacc[((size_t)split * B_ + q0 + w * 16 + lk * 4 + r) * SQ_ + col] = acc[ct][r];
    }
  }
  if (lrow == 0) {
#pragma unroll
    for (int r = 0; r < 4; ++r) {
      size_t i = (size_t)split * B_ + q0 + w * 16 + lk * 4 + r;
      marr[i] = m_[r];
      larr[i] = l_[r];
    }
  }
}

// ---------------------------------------------------------------------------
// combine splits -> o1b bf16 [8192][160] (pads zeroed)
// ---------------------------------------------------------------------------
__global__ __launch_bounds__(256) void combine_k(
    const float* __restrict__ oacc, const float* __restrict__ marr,
    const float* __restrict__ larr, u16* __restrict__ o1b)
{
  int idx = blockIdx.x * 256 + threadIdx.x;
  if (idx >= B_ * 160) return;
  int n = idx / 160, d = idx - n * 160;
  float v = 0.f;
  if (d < QD_) {
    float m = -1e30f;
#pragma unroll
    for (int s = 0; s < NSPLIT; ++s) m = fmaxf(m, marr[s * B_ + n]);
    float l = 0.f, o = 0.f;
#pragma unroll
    for (int s = 0; s < NSPLIT; ++s) {
      float e = __expf(marr[s * B_ + n] - m);
      l += larr[s * B_ + n] * e;
      o += oacc[((size_t)s * B_ + n) * SQ_ + d] * e;
    }
    v = o / l;
  }
  o1b[idx] = f2bf(v);
}

// ---------------------------------------------------------------------------
extern "C" void kernel_launch(void* const* d_in, const int* in_sizes, int n_in,
                              void* d_out, int out_size, void* d_ws, size_t ws_size,
                              hipStream_t stream)
{
  const float* emb0 = (const float*)d_in[0];
  const float* ef0  = (const float*)d_in[1];
  const float* td0  = (const float*)d_in[2];
  const float* emb1 = (const float*)d_in[3];
  const float* ef1  = (const float*)d_in[4];
  const float* td1  = (const float*)d_in[5];
  const float* emb2 = (const float*)d_in[6];
  const float* Wq = (const float*)d_in[7];  const float* bq = (const float*)d_in[8];
  const float* Wk = (const float*)d_in[9];  const float* bk = (const float*)d_in[10];
  const float* Wv = (const float*)d_in[11]; const float* bv = (const float*)d_in[12];
  const float* Wo = (const float*)d_in[13]; const float* bo = (const float*)d_in[14];
  const float* W1 = (const float*)d_in[15]; const float* b1 = (const float*)d_in[16];
  const float* W2 = (const float*)d_in[17]; const float* b2 = (const float*)d_in[18];
  float* out = (float*)d_out;

  char* ws = (char*)d_ws;
  u16* wb   = (u16*)ws;
  u16* wkv  = wb;
  u16* wq_b = wb + 377856;
  u16* wo_b = wb + 400896;
  u16* w1_b = wb + 423936;
  u16* w2_b = wb + 465408;
  float* kp0 = (float*)(ws + 1048576);    // [40960][132] f32
  float* vp0 = (float*)(ws + 22675456);
  float* qp0 = (float*)(ws + 44302336);
  u16*   o0b = (u16*)(ws + 65929216);     // [40960][160] bf16
  u16*   cat0= (u16*)(ws + 1048576);      // [40960][288] bf16 (overlays kp0/vp0)
  u16*   h0  = (u16*)(ws + 24641536);     // [40960][128] bf16
  u16*   qp1b = (u16*)(ws + 44302336);    // [8192][160]
  u16*   kp1b = (u16*)(ws + 46923776);
  u16*   vp1T = (u16*)(ws + 49545216);    // [144][8192]
  u16*   o1b  = (u16*)(ws + 51904512);    // [8192][160]
  float* marr = (float*)(ws + 54525952);
  float* larr = (float*)(ws + 54657024);
  u16*   cat1 = (u16*)(ws + 54788096);    // [8192][288]
  u16*   h1   = (u16*)(ws + 59506688);    // [8192][128]
  float* oacc = (float*)(ws + 79036416);  // [4][8192][132]

  const float scale = 0.08804509063256238f;  // 1/sqrt(129)

  convw_k<<<1890, 256, 0, stream>>>(Wq, Wk, Wv, Wo, W1, W2, wb);

  // ---- i = 0 -------------------------------------------------------------
  // kp0,vp0 (f32) : nf-gather, N-split 2
  gmm_k<2, false, 0, 0, true><<<1280, 256, 0, stream>>>(
      41, KDP, 2, emb0, 0, ef0, td0, wkv,
      bk, kp0, SQ_, QD_, bv, vp0, SQ_, 1.f);
  // qp0 (f32)
  gmm_k<1, false, 0, 0, false><<<640, 256, 0, stream>>>(
      5, 160, 1, emb1, 0, nullptr, td1, wq_b,
      bq, qp0, SQ_, QD_, nullptr, nullptr, 0, scale);
  attn0_k<<<B_ / 4, 256, 0, stream>>>(qp0, kp0, vp0, o0b);
  hipMemsetAsync(cat0, 0, 23592960, stream);
  embpack_k<<<(BK_ * 128 + 255) / 256, 256, 0, stream>>>(emb1, cat0, BK_);
  // Wo -> cat0 cols 0..128 (bf16)
  gmm_k<0, false, 1, 0, false><<<640, 256, 0, stream>>>(
      5, 160, 1, o0b, 160, nullptr, nullptr, wo_b,
      bo, cat0, 288, QD_, nullptr, nullptr, 0, 1.f);
  // W1 relu -> h0 (bf16)
  gmm_k<0, true, 1, 0, false><<<640, 256, 0, stream>>>(
      9, 288, 1, cat0, 288, nullptr, nullptr, w1_b,
      b1, h0, 128, 128, nullptr, nullptr, 0, 1.f);
  // W2 -> out (f32)
  gmm_k<0, false, 0, 0, false><<<640, 256, 0, stream>>>(
      4, 128, 1, h0, 128, nullptr, nullptr, w2_b,
      b2, out, 128, 128, nullptr, nullptr, 0, 1.f);

  // ---- i = 1 -------------------------------------------------------------
  hipMemsetAsync(qp1b, 0, 2621440, stream);
  hipMemsetAsync(kp1b, 0, 2621440, stream);
  hipMemsetAsync(vp1T, 0, 2359296, stream);
  gmm_k<2, false, 1, 2, true><<<256, 256, 0, stream>>>(
      41, KDP, 2, emb1, 0, ef1, td1, wkv,
      bk, kp1b, QPAD, QD_, bv, vp1T, B_, 1.f);
  gmm_k<1, false, 1, 0, false><<<128, 256, 0, stream>>>(
      5, 160, 1, emb2, 0, nullptr, nullptr, wq_b,
      bq, qp1b, QPAD, QD_, nullptr, nullptr, 0, scale);
  flashm_k<<<(B_ / 64) * NSPLIT, 256, 0, stream>>>(qp1b, kp1b, vp1T, oacc, marr, larr);
  combine_k<<<(B_ * 160 + 255) / 256, 256, 0, stream>>>(oacc, marr, larr, o1b);
  hipMemsetAsync(cat1, 0, 4718592, stream);
  embpack_k<<<(B_ * 128 + 255) / 256, 256, 0, stream>>>(emb2, cat1, B_);
  gmm_k<0, false, 1, 0, false><<<128, 256, 0, stream>>>(
      5, 160, 1, o1b, 160, nullptr, nullptr, wo_b,
      bo, cat1, 288, QD_, nullptr, nullptr, 0, 1.f);
  gmm_k<0, true, 1, 0, false><<<128, 256, 0, stream>>>(
      9, 288, 1, cat1, 288, nullptr, nullptr, w1_b,
      b1, h1, 128, 128, nullptr, nullptr, 0, 1.f);
  gmm_k<0, false, 0, 0, false><<<128, 256, 0, stream>>>(
      4, 128, 1, h1, 128, nullptr, nullptr, w2_b,
      b2, out + (size_t)BK_ * D_, 128, 128, nullptr, nullptr, 0, 1.f);
}

// Round 8
// 659.744 us; speedup vs baseline: 1.0032x; 1.0032x over previous
//
#include <hip/hip_runtime.h>

#define B_   8192
#define K_   5
#define D_   128
#define QD_  129
#define KD_  1285
#define SQ_  132      // padded fp32 row stride
#define BK_  40960    // B_*K_
#define QPAD 160      // bf16 k-dim padding (5 x 32)
#define VPAD 144      // bf16 out-dim padding (9 x 16)
#define KDP  1312     // KD_ padded to 41*32

typedef unsigned short u16;
typedef unsigned int   u32;
typedef __attribute__((ext_vector_type(8))) short bf8_t;
typedef __attribute__((ext_vector_type(4))) float f4_t;
typedef __attribute__((address_space(3))) u32 lds_u32;
typedef __attribute__((address_space(1))) const u32 glob_u32;

#define MFMA16(a, b, c) __builtin_amdgcn_mfma_f32_16x16x32_bf16(a, b, c, 0, 0, 0)

__device__ __forceinline__ u16 f2bf(float x) {
  u32 u = __float_as_uint(x);
  u = (u + 0x7fffu + ((u >> 16) & 1u)) >> 16;
  return (u16)u;
}
__device__ __forceinline__ u32 pack2(float a, float b) {
  return (u32)f2bf(a) | ((u32)f2bf(b) << 16);
}
// LDS W layout: row stride 32 u16 (64B), 8-u16 sub-blocks XOR-swizzled by row.
__device__ __forceinline__ int swz8(int row, int seg) {
  return (row << 5) + (((seg ^ (row >> 1)) & 3) << 3);
}
__device__ __forceinline__ void gload16(const u16* src, u16* ldsdst) {
  __builtin_amdgcn_global_load_lds((glob_u32*)src, (lds_u32*)ldsdst, 16, 0, 0);
}
#define WAIT_VM0() asm volatile("s_waitcnt vmcnt(0)" ::: "memory")

// ---------------------------------------------------------------------------
// One-time weight conversion fp32 -> bf16 with zero padding.
//   wkv [288][1312] @0        rows 0-128 Wk, 129-257 Wv
//   wq  [144][160]  @377856
//   wo  [144][160]  @400896
//   w1  [144][288]  @423936
//   w2  [144][128]  @465408
// ---------------------------------------------------------------------------
__global__ __launch_bounds__(256) void convw_k(
    const float* __restrict__ Wq, const float* __restrict__ Wk,
    const float* __restrict__ Wv, const float* __restrict__ Wo,
    const float* __restrict__ W1, const float* __restrict__ W2,
    u16* __restrict__ wb)
{
  int idx = blockIdx.x * 256 + threadIdx.x;
  if (idx < 377856) {
    int r = idx / KDP, c = idx - r * KDP;
    float v = 0.f;
    if (c < KD_) {
      if (r < 129) v = Wk[r * KD_ + c];
      else if (r < 258) v = Wv[(r - 129) * KD_ + c];
    }
    wb[idx] = f2bf(v);
    return;
  }
  int i2 = idx - 377856;
  if (i2 < 23040) {
    int r = i2 / 160, c = i2 - r * 160;
    wb[idx] = f2bf((r < 129 && c < 129) ? Wq[r * 129 + c] : 0.f);
    return;
  }
  i2 -= 23040;
  if (i2 < 23040) {
    int r = i2 / 160, c = i2 - r * 160;
    wb[idx] = f2bf((r < 129 && c < 129) ? Wo[r * 129 + c] : 0.f);
    return;
  }
  i2 -= 23040;
  if (i2 < 41472) {
    int r = i2 / 288, c = i2 - r * 288;
    wb[idx] = f2bf((r < 128 && c < 257) ? W1[r * 257 + c] : 0.f);
    return;
  }
  i2 -= 41472;
  if (i2 < 18432) {
    int r = i2 / 128, c = i2 - r * 128;
    wb[idx] = f2bf(r < 128 ? W2[r * 128 + c] : 0.f);
  }
}

// ---------------------------------------------------------------------------
// Unified bf16 MFMA GEMM. BM=64 rows, BN=144 cols per block, 256 thr,
// 4 waves as 4Mx1N (wave: 16 rows x 144 cols, 9 MFMA/step).
// A operand DIRECT TO REGISTERS (no LDS):
//   GA=0: A bf16 row-major, 1 bf8 load/lane/step.
//   GA=1: A=[emb f32 [n][128] | td | 0], 8 f32 gather + cvt.
//   GA=2: A=nf gather (emb,ef,td fused concat), 8 f32 gather + cvt.
// W staged in LDS via global_load_lds (pre-swizzled source), double-buffered.
// nch column-halves (nch=2 splits N=288 across block pairs sharing A rows).
// Epilogue col = colh*144 + ct*16 + lrow: col<N0 -> out0, else DUAL -> out1.
// OM: 0=f32 row-major, 1=bf16 row-major, 2=bf16 transposed.
// ---------------------------------------------------------------------------
template<int GA, bool RELU, int OM0, int OM1, bool DUAL>
__global__ __launch_bounds__(256) void gmm_k(
    int nK, int Kw, int nch,
    const void* __restrict__ A, int ast,
    const float* __restrict__ g1, const float* __restrict__ g2,
    const u16* __restrict__ Wb,
    const float* __restrict__ b0, void* __restrict__ out0, int ost0, int N0,
    const float* __restrict__ b1, void* __restrict__ out1, int ost1,
    float scale)
{
  __shared__ u16 Ws_[2][9 * 512];
  const int t = threadIdx.x, lane = t & 63, w = t >> 6;
  const int lrow = lane & 15, lk = lane >> 4;
  const int bid = blockIdx.x;
  const int x = bid / nch, colh = bid - x * nch;
  const int n0 = x * 64;
  const int colofs = colh * 144;
  const int drow = lane >> 2, dseg = lane & 3;
  const int arow = n0 + w * 16 + lrow;

  f4_t acc[9];
#pragma unroll
  for (int ct = 0; ct < 9; ++ct) acc[ct] = (f4_t){0.f, 0.f, 0.f, 0.f};

  bf8_t afE, afO;
  float rE[8], rO[8];

  auto issueR = [&](int kst, float (&r)[8]) {
    const int cb = kst * 32 + lk * 8;
#pragma unroll
    for (int i = 0; i < 8; ++i) {
      int c = cb + i;
      if (GA == 1) {
        uintptr_t pa = (uintptr_t)((const float*)A + (arow << 7) + c);
        uintptr_t pt = (uintptr_t)(g2 ? (g2 + arow) : (const float*)A);
        uintptr_t sel = (c < 128) ? pa : pt;
        float v = *(const float*)sel;
        r[i] = (c < 128) ? v : ((c == 128 && g2) ? v : 0.f);
      } else {
        int j = c / 257;
        int rr = c - j * 257;
        int base = (arow * 5 + j) << 7;
        uintptr_t pe = (uintptr_t)((const float*)A + base + rr);
        uintptr_t pf = (uintptr_t)(g1 + base + (rr - 128));
        uintptr_t pt = (uintptr_t)(g2 + arow * 5 + j);
        uintptr_t sel = (rr < 128) ? pe : (rr < 256) ? pf : pt;
        if (j >= 5) sel = (uintptr_t)g2;
        float v = *(const float*)sel;
        r[i] = (j < 5) ? v : 0.f;
      }
    }
  };
  auto cvt8 = [&](const float (&r)[8]) -> bf8_t {
    union { bf8_t v; u32 u[4]; } xx;
#pragma unroll
    for (int i = 0; i < 4; ++i) xx.u[i] = pack2(r[2 * i], r[2 * i + 1]);
    return xx.v;
  };
  auto loadAf = [&](int kst) -> bf8_t {
    return *(const bf8_t*)((const u16*)A + (size_t)arow * ast + kst * 32 + lk * 8);
  };
  auto dmaW = [&](int kst, u16* wbuf) {
    const int c0 = kst * 32;
#pragma unroll
    for (int si = 0; si < 3; ++si) {
      int s = w + si * 4;            // wave-uniform
      if (s < 9) {
        int rr = colofs + s * 16 + drow;
        int sseg = (dseg ^ (rr >> 1)) & 3;
        gload16(&Wb[(size_t)rr * Kw + c0 + sseg * 8], wbuf + s * 512);
      }
    }
  };
  auto compute = [&](bf8_t af, const u16* wsb) {
#pragma unroll
    for (int ct = 0; ct < 9; ++ct) {
      bf8_t bf = *(const bf8_t*)&wsb[swz8(ct * 16 + lrow, lk)];
      acc[ct] = MFMA16(af, bf, acc[ct]);
    }
  };

  // prologue: tile 0
  if (GA == 0) afE = loadAf(0); else issueR(0, rE);
  dmaW(0, Ws_[0]);
  WAIT_VM0();
  if (GA != 0) afE = cvt8(rE);
  __builtin_amdgcn_s_barrier();

  int cur = 0, k = 0;
  while (true) {
    // even-slot step (uses afE)
    if (k + 1 < nK) {
      if (GA == 0) afO = loadAf(k + 1); else issueR(k + 1, rO);
      dmaW(k + 1, Ws_[cur ^ 1]);
    }
    compute(afE, Ws_[cur]);
    if (k + 1 >= nK) break;
    WAIT_VM0();
    if (GA != 0) afO = cvt8(rO);
    __builtin_amdgcn_s_barrier();
    cur ^= 1; ++k;
    // odd-slot step (uses afO)
    if (k + 1 < nK) {
      if (GA == 0) afE = loadAf(k + 1); else issueR(k + 1, rE);
      dmaW(k + 1, Ws_[cur ^ 1]);
    }
    compute(afO, Ws_[cur]);
    if (k + 1 >= nK) break;
    WAIT_VM0();
    if (GA != 0) afE = cvt8(rE);
    __builtin_amdgcn_s_barrier();
    cur ^= 1; ++k;
  }

  // epilogue
#pragma unroll
  for (int ct = 0; ct < 9; ++ct) {
    const int col = colofs + ct * 16 + lrow;
#pragma unroll
    for (int r = 0; r < 4; ++r) {
      const int n = n0 + w * 16 + lk * 4 + r;
      float v = acc[ct][r];
      if (col < N0) {
        v = (v + b0[col]) * scale;
        if (RELU) v = fmaxf(v, 0.f);
        if (OM0 == 0)      ((float*)out0)[(size_t)n * ost0 + col] = v;
        else if (OM0 == 1) ((u16*)out0)[(size_t)n * ost0 + col] = f2bf(v);
        else               ((u16*)out0)[(size_t)col * ost0 + n] = f2bf(v);
      } else if (DUAL) {
        int o = col - N0;
        if (o < 129) {
          v = (v + b1[o]) * scale;
          if (RELU) v = fmaxf(v, 0.f);
          if (OM1 == 0)      ((float*)out1)[(size_t)n * ost1 + o] = v;
          else if (OM1 == 1) ((u16*)out1)[(size_t)n * ost1 + o] = f2bf(v);
          else               ((u16*)out1)[(size_t)o * ost1 + n] = f2bf(v);
        }
      }
    }
  }
}

// ---------------------------------------------------------------------------
// emb pack: f32 [rows][128] -> bf16 into dst cols 129..256 (stride 288)
// ---------------------------------------------------------------------------
__global__ __launch_bounds__(256) void embpack_k(
    const float* __restrict__ src, u16* __restrict__ dst, int rows)
{
  int idx = blockIdx.x * 256 + threadIdx.x;
  if (idx >= rows * 128) return;
  int n = idx >> 7, c = idx & 127;
  dst[(size_t)n * 288 + 129 + c] = f2bf(src[idx]);
}

// ---------------------------------------------------------------------------
// i=0 attention: per batch b, 5 queries x 5 keys, dim 129.
// ---------------------------------------------------------------------------
__global__ __launch_bounds__(256) void attn0_k(
    const float* __restrict__ qp, const float* __restrict__ kp,
    const float* __restrict__ vp, u16* __restrict__ o0b)
{
  __shared__ float qs[4][5][SQ_], ks[4][5][SQ_], vs[4][5][SQ_];
  __shared__ float ps[4][5][8];
  const int t = threadIdx.x;
  const int bbase = blockIdx.x * 4;
  for (int idx = t; idx < 4 * 5 * SQ_; idx += 256) {
    int bl = idx / (5 * SQ_);
    int rem = idx - bl * 5 * SQ_;
    int row = rem / SQ_;
    int d = rem - row * SQ_;
    int n = (bbase + bl) * 5 + row;
    float qv = 0.f, kv = 0.f, vv = 0.f;
    if (d < QD_) { qv = qp[n * SQ_ + d]; kv = kp[n * SQ_ + d]; vv = vp[n * SQ_ + d]; }
    qs[bl][row][d] = qv; ks[bl][row][d] = kv; vs[bl][row][d] = vv;
  }
  __syncthreads();
  const int w = t >> 6, lane = t & 63;
  if (lane < 25) {
    int qq = lane / 5, kk = lane - (lane / 5) * 5;
    float s = 0.f;
    for (int c = 0; c < QD_; ++c) s += qs[w][qq][c] * ks[w][kk][c];
    ps[w][qq][kk] = s;
  }
  __syncthreads();
  if (lane < 5) {
    float m = -1e30f;
#pragma unroll
    for (int k = 0; k < 5; ++k) m = fmaxf(m, ps[w][lane][k]);
    float l = 0.f; float e[5];
#pragma unroll
    for (int k = 0; k < 5; ++k) { e[k] = __expf(ps[w][lane][k] - m); l += e[k]; }
    float inv = 1.f / l;
#pragma unroll
    for (int k = 0; k < 5; ++k) ps[w][lane][k] = e[k] * inv;
  }
  __syncthreads();
  for (int d = lane; d < 160; d += 64) {
#pragma unroll
    for (int qq = 0; qq < 5; ++qq) {
      float o = 0.f;
      if (d < QD_) {
#pragma unroll
        for (int k = 0; k < 5; ++k) o += ps[w][qq][k] * vs[w][k][d];
      }
      o0b[(size_t)((bbase + w) * 5 + qq) * 160 + d] = f2bf(o);
    }
  }
}

// ---------------------------------------------------------------------------
// i=1 MFMA flash attention (unchanged).
// ---------------------------------------------------------------------------
#define KSS 168
#define VSS 72
#define PSS 72
#define NSPLIT 4
__global__ __launch_bounds__(256) void flashm_k(
    const u16* __restrict__ qp, const u16* __restrict__ kp,
    const u16* __restrict__ vpT, float* __restrict__ oacc,
    float* __restrict__ marr, float* __restrict__ larr)
{
  __shared__ u16 ks[64 * KSS];
  __shared__ u16 vsT[VPAD * VSS];
  __shared__ u16 ps[64 * PSS];
  const int t = threadIdx.x;
  const int split = blockIdx.x & (NSPLIT - 1);
  const int q0 = (blockIdx.x >> 2) * 64;
  const int w = t >> 6, lane = t & 63;
  const int lrow = lane & 15, lk = lane >> 4;

  bf8_t qf[5];
  {
    const u16* qrow = qp + (size_t)(q0 + w * 16 + lrow) * QPAD;
#pragma unroll
    for (int kst = 0; kst < 5; ++kst)
      qf[kst] = *(const bf8_t*)(qrow + kst * 32 + lk * 8);
  }

  f4_t acc[9];
#pragma unroll
  for (int ct = 0; ct < 9; ++ct) acc[ct] = (f4_t){0.f, 0.f, 0.f, 0.f};
  float m_[4] = {-1e30f, -1e30f, -1e30f, -1e30f};
  float l_[4] = {0.f, 0.f, 0.f, 0.f};

  const int kbase = split * (B_ / NSPLIT);
  for (int tile = 0; tile < (B_ / NSPLIT) / 64; ++tile) {
    const int k0 = kbase + tile * 64;
    __syncthreads();
    for (int e = t; e < 64 * 20; e += 256) {
      int r = e / 20, c = e - r * 20;
      *(uint4*)&ks[r * KSS + c * 8] = *(const uint4*)(kp + (size_t)(k0 + r) * QPAD + c * 8);
    }
    for (int e = t; e < VPAD * 8; e += 256) {
      int r = e >> 3, c = e & 7;
      *(uint4*)&vsT[r * VSS + c * 8] = *(const uint4*)(vpT + (size_t)r * B_ + k0 + c * 8);
    }
    __syncthreads();

    f4_t s[4];
#pragma unroll
    for (int ct = 0; ct < 4; ++ct) s[ct] = (f4_t){0.f, 0.f, 0.f, 0.f};
#pragma unroll
    for (int kst = 0; kst < 5; ++kst) {
#pragma unroll
      for (int ct = 0; ct < 4; ++ct) {
        bf8_t b = *(const bf8_t*)&ks[(ct * 16 + lrow) * KSS + kst * 32 + lk * 8];
        s[ct] = MFMA16(qf[kst], b, s[ct]);
      }
    }

    float pm[4];
#pragma unroll
    for (int r = 0; r < 4; ++r) {
      pm[r] = fmaxf(fmaxf(s[0][r], s[1][r]), fmaxf(s[2][r], s[3][r]));
#pragma unroll
      for (int mk = 1; mk <= 8; mk <<= 1) pm[r] = fmaxf(pm[r], __shfl_xor(pm[r], mk));
    }
    float cf[4], rs[4];
#pragma unroll
    for (int r = 0; r < 4; ++r) {
      float mn = fmaxf(m_[r], pm[r]);
      cf[r] = __expf(m_[r] - mn);
      m_[r] = mn;
      rs[r] = 0.f;
    }
#pragma unroll
    for (int ct = 0; ct < 4; ++ct) {
#pragma unroll
      for (int r = 0; r < 4; ++r) {
        float p = __expf(s[ct][r] - m_[r]);
        ps[(w * 16 + lk * 4 + r) * PSS + ct * 16 + lrow] = f2bf(p);
        rs[r] += p;
      }
    }
#pragma unroll
    for (int r = 0; r < 4; ++r) {
#pragma unroll
      for (int mk = 1; mk <= 8; mk <<= 1) rs[r] += __shfl_xor(rs[r], mk);
      l_[r] = l_[r] * cf[r] + rs[r];
    }
#pragma unroll
    for (int ct = 0; ct < 9; ++ct) {
#pragma unroll
      for (int r = 0; r < 4; ++r) acc[ct][r] *= cf[r];
    }
    __syncthreads();

#pragma unroll
    for (int kst = 0; kst < 2; ++kst) {
      bf8_t a = *(const bf8_t*)&ps[(w * 16 + lrow) * PSS + kst * 32 + lk * 8];
#pragma unroll
      for (int ct = 0; ct < 9; ++ct) {
        bf8_t b = *(const bf8_t*)&vsT[(ct * 16 + lrow) * VSS + kst * 32 + lk * 8];
        acc[ct] = MFMA16(a, b, acc[ct]);
      }
    }
  }

#pragma unroll
  for (int ct = 0; ct < 9; ++ct) {
    const int col = ct * 16 + lrow;
    if (col < SQ_) {
#pragma unroll
      for (int r = 0; r < 4; ++r)
        oacc[((size_t)split * B_ + q0 + w * 16 + lk * 4 + r) * SQ_ + col] = acc[ct][r];
    }
  }
  if (lrow == 0) {
#pragma unroll
    for (int r = 0; r < 4; ++r) {
      size_t i = (size_t)split * B_ + q0 + w * 16 + lk * 4 + r;
      marr[i] = m_[r];
      larr[i] = l_[r];
    }
  }
}

// ---------------------------------------------------------------------------
// combine splits -> o1b bf16 [8192][160] (pads zeroed)
// ---------------------------------------------------------------------------
__global__ __launch_bounds__(256) void combine_k(
    const float* __restrict__ oacc, const float* __restrict__ marr,
    const float* __restrict__ larr, u16* __restrict__ o1b)
{
  int idx = blockIdx.x * 256 + threadIdx.x;
  if (idx >= B_ * 160) return;
  int n = idx / 160, d = idx - n * 160;
  float v = 0.f;
  if (d < QD_) {
    float m = -1e30f;
#pragma unroll
    for (int s = 0; s < NSPLIT; ++s) m = fmaxf(m, marr[s * B_ + n]);
    float l = 0.f, o = 0.f;
#pragma unroll
    for (int s = 0; s < NSPLIT; ++s) {
      float e = __expf(marr[s * B_ + n] - m);
      l += larr[s * B_ + n] * e;
      o += oacc[((size_t)s * B_ + n) * SQ_ + d] * e;
    }
    v = o / l;
  }
  o1b[idx] = f2bf(v);
}

// ---------------------------------------------------------------------------
extern "C" void kernel_launch(void* const* d_in, const int* in_sizes, int n_in,
                              void* d_out, int out_size, void* d_ws, size_t ws_size,
                              hipStream_t stream)
{
  const float* emb0 = (const float*)d_in[0];
  const float* ef0  = (const float*)d_in[1];
  const float* td0  = (const float*)d_in[2];
  const float* emb1 = (const float*)d_in[3];
  const float* ef1  = (const float*)d_in[4];
  const float* td1  = (const float*)d_in[5];
  const float* emb2 = (const float*)d_in[6];
  const float* Wq = (const float*)d_in[7];  const float* bq = (const float*)d_in[8];
  const float* Wk = (const float*)d_in[9];  const float* bk = (const float*)d_in[10];
  const float* Wv = (const float*)d_in[11]; const float* bv = (const float*)d_in[12];
  const float* Wo = (const float*)d_in[13]; const float* bo = (const float*)d_in[14];
  const float* W1 = (const float*)d_in[15]; const float* b1 = (const float*)d_in[16];
  const float* W2 = (const float*)d_in[17]; const float* b2 = (const float*)d_in[18];
  float* out = (float*)d_out;

  char* ws = (char*)d_ws;
  u16* wb   = (u16*)ws;
  u16* wkv  = wb;
  u16* wq_b = wb + 377856;
  u16* wo_b = wb + 400896;
  u16* w1_b = wb + 423936;
  u16* w2_b = wb + 465408;
  float* kp0 = (float*)(ws + 1048576);    // [40960][132] f32
  float* vp0 = (float*)(ws + 22675456);
  float* qp0 = (float*)(ws + 44302336);
  u16*   o0b = (u16*)(ws + 65929216);     // [40960][160] bf16
  u16*   cat0= (u16*)(ws + 1048576);      // [40960][288] bf16 (overlays kp0/vp0)
  u16*   h0  = (u16*)(ws + 24641536);     // [40960][128] bf16
  u16*   qp1b = (u16*)(ws + 44302336);    // [8192][160]
  u16*   kp1b = (u16*)(ws + 46923776);
  u16*   vp1T = (u16*)(ws + 49545216);    // [144][8192]
  u16*   o1b  = (u16*)(ws + 51904512);    // [8192][160]
  float* marr = (float*)(ws + 54525952);
  float* larr = (float*)(ws + 54657024);
  u16*   cat1 = (u16*)(ws + 54788096);    // [8192][288]
  u16*   h1   = (u16*)(ws + 59506688);    // [8192][128]
  float* oacc = (float*)(ws + 79036416);  // [4][8192][132]

  const float scale = 0.08804509063256238f;  // 1/sqrt(129)

  convw_k<<<1890, 256, 0, stream>>>(Wq, Wk, Wv, Wo, W1, W2, wb);

  // ---- i = 0 -------------------------------------------------------------
  // kp0,vp0 (f32) : nf-gather, N-split 2
  gmm_k<2, false, 0, 0, true><<<1280, 256, 0, stream>>>(
      41, KDP, 2, emb0, 0, ef0, td0, wkv,
      bk, kp0, SQ_, QD_, bv, vp0, SQ_, 1.f);
  // qp0 (f32)
  gmm_k<1, false, 0, 0, false><<<640, 256, 0, stream>>>(
      5, 160, 1, emb1, 0, nullptr, td1, wq_b,
      bq, qp0, SQ_, QD_, nullptr, nullptr, 0, scale);
  attn0_k<<<B_ / 4, 256, 0, stream>>>(qp0, kp0, vp0, o0b);
  hipMemsetAsync(cat0, 0, 23592960, stream);
  embpack_k<<<(BK_ * 128 + 255) / 256, 256, 0, stream>>>(emb1, cat0, BK_);
  // Wo -> cat0 cols 0..128 (bf16)
  gmm_k<0, false, 1, 0, false><<<640, 256, 0, stream>>>(
      5, 160, 1, o0b, 160, nullptr, nullptr, wo_b,
      bo, cat0, 288, QD_, nullptr, nullptr, 0, 1.f);
  // W1 relu -> h0 (bf16)
  gmm_k<0, true, 1, 0, false><<<640, 256, 0, stream>>>(
      9, 288, 1, cat0, 288, nullptr, nullptr, w1_b,
      b1, h0, 128, 128, nullptr, nullptr, 0, 1.f);
  // W2 -> out (f32)
  gmm_k<0, false, 0, 0, false><<<640, 256, 0, stream>>>(
      4, 128, 1, h0, 128, nullptr, nullptr, w2_b,
      b2, out, 128, 128, nullptr, nullptr, 0, 1.f);

  // ---- i = 1 -------------------------------------------------------------
  hipMemsetAsync(qp1b, 0, 2621440, stream);
  hipMemsetAsync(kp1b, 0, 2621440, stream);
  hipMemsetAsync(vp1T, 0, 2359296, stream);
  gmm_k<2, false, 1, 2, true><<<256, 256, 0, stream>>>(
      41, KDP, 2, emb1, 0, ef1, td1, wkv,
      bk, kp1b, QPAD, QD_, bv, vp1T, B_, 1.f);
  gmm_k<1, false, 1, 0, false><<<128, 256, 0, stream>>>(
      5, 160, 1, emb2, 0, nullptr, nullptr, wq_b,
      bq, qp1b, QPAD, QD_, nullptr, nullptr, 0, scale);
  flashm_k<<<(B_ / 64) * NSPLIT, 256, 0, stream>>>(qp1b, kp1b, vp1T, oacc, marr, larr);
  combine_k<<<(B_ * 160 + 255) / 256, 256, 0, stream>>>(oacc, marr, larr, o1b);
  hipMemsetAsync(cat1, 0, 4718592, stream);
  embpack_k<<<(B_ * 128 + 255) / 256, 256, 0, stream>>>(emb2, cat1, B_);
  gmm_k<0, false, 1, 0, false><<<128, 256, 0, stream>>>(
      5, 160, 1, o1b, 160, nullptr, nullptr, wo_b,
      bo, cat1, 288, QD_, nullptr, nullptr, 0, 1.f);
  gmm_k<0, true, 1, 0, false><<<128, 256, 0, stream>>>(
      9, 288, 1, cat1, 288, nullptr, nullptr, w1_b,
      b1, h1, 128, 128, nullptr, nullptr, 0, 1.f);
  gmm_k<0, false, 0, 0, false><<<128, 256, 0, stream>>>(
      4, 128, 1, h1, 128, nullptr, nullptr, w2_b,
      b2, out + (size_t)BK_ * D_, 128, 128, nullptr, nullptr, 0, 1.f);
}

// Round 9
// 508.485 us; speedup vs baseline: 1.3016x; 1.2975x over previous
//
#include <hip/hip_runtime.h>

#define B_   8192
#define K_   5
#define D_   128
#define QD_  129
#define KD_  1285
#define SQ_  132      // padded fp32 row stride
#define BK_  40960    // B_*K_
#define QPAD 160      // bf16 k-dim padding (5 x 32)
#define VPAD 144      // bf16 out-dim padding (9 x 16)
#define KDP  1312     // KD_ padded to 41*32

typedef unsigned short u16;
typedef unsigned int   u32;
typedef __attribute__((ext_vector_type(8))) short bf8_t;
typedef __attribute__((ext_vector_type(4))) float f4_t;
typedef __attribute__((address_space(3))) u32 lds_u32;
typedef __attribute__((address_space(1))) const u32 glob_u32;

#define MFMA16(a, b, c) __builtin_amdgcn_mfma_f32_16x16x32_bf16(a, b, c, 0, 0, 0)

__device__ __forceinline__ u16 f2bf(float x) {
  u32 u = __float_as_uint(x);
  u = (u + 0x7fffu + ((u >> 16) & 1u)) >> 16;
  return (u16)u;
}
__device__ __forceinline__ u32 pack2(float a, float b) {
  return (u32)f2bf(a) | ((u32)f2bf(b) << 16);
}
// LDS W layout: row stride 32 u16 (64B), 8-u16 sub-blocks XOR-swizzled by row.
__device__ __forceinline__ int swz8(int row, int seg) {
  return (row << 5) + (((seg ^ (row >> 1)) & 3) << 3);
}
__device__ __forceinline__ void gload16(const u16* src, u16* ldsdst) {
  __builtin_amdgcn_global_load_lds((glob_u32*)src, (lds_u32*)ldsdst, 16, 0, 0);
}
#define WAIT_VM0() asm volatile("s_waitcnt vmcnt(0)" ::: "memory")

// ---------------------------------------------------------------------------
// One-time weight conversion fp32 -> bf16 with zero padding.
//   wkv [288][1312] @0        rows 0-128 Wk, 129-257 Wv
//   wq  [144][160]  @377856
//   wo  [144][160]  @400896
//   w1  [144][288]  @423936
//   w2  [144][128]  @465408
// ---------------------------------------------------------------------------
__global__ __launch_bounds__(256) void convw_k(
    const float* __restrict__ Wq, const float* __restrict__ Wk,
    const float* __restrict__ Wv, const float* __restrict__ Wo,
    const float* __restrict__ W1, const float* __restrict__ W2,
    u16* __restrict__ wb)
{
  int idx = blockIdx.x * 256 + threadIdx.x;
  if (idx < 377856) {
    int r = idx / KDP, c = idx - r * KDP;
    float v = 0.f;
    if (c < KD_) {
      if (r < 129) v = Wk[r * KD_ + c];
      else if (r < 258) v = Wv[(r - 129) * KD_ + c];
    }
    wb[idx] = f2bf(v);
    return;
  }
  int i2 = idx - 377856;
  if (i2 < 23040) {
    int r = i2 / 160, c = i2 - r * 160;
    wb[idx] = f2bf((r < 129 && c < 129) ? Wq[r * 129 + c] : 0.f);
    return;
  }
  i2 -= 23040;
  if (i2 < 23040) {
    int r = i2 / 160, c = i2 - r * 160;
    wb[idx] = f2bf((r < 129 && c < 129) ? Wo[r * 129 + c] : 0.f);
    return;
  }
  i2 -= 23040;
  if (i2 < 41472) {
    int r = i2 / 288, c = i2 - r * 288;
    wb[idx] = f2bf((r < 128 && c < 257) ? W1[r * 257 + c] : 0.f);
    return;
  }
  i2 -= 41472;
  if (i2 < 18432) {
    int r = i2 / 128, c = i2 - r * 128;
    wb[idx] = f2bf(r < 128 ? W2[r * 128 + c] : 0.f);
  }
}

// ---------------------------------------------------------------------------
// nf pack: gather [emb|ef|td]x5 fp32 -> bf16 [rows][KDP], zero-padded.
// 4 consecutive cols per thread, one division per element ONCE total.
// ---------------------------------------------------------------------------
__global__ __launch_bounds__(256) void packnf_k(
    const float* __restrict__ emb, const float* __restrict__ ef,
    const float* __restrict__ td, u16* __restrict__ dst, int nofs, int rows)
{
  int idx = blockIdx.x * 256 + threadIdx.x;
  if (idx >= rows * 328) return;
  int nr = idx / 328, q = idx - nr * 328;
  const int n = nofs + nr;
  const int c0 = q * 4;
  u16 o[4];
#pragma unroll
  for (int i = 0; i < 4; ++i) {
    int c = c0 + i;
    float v = 0.f;
    if (c < KD_) {
      int j = c / 257, r = c - j * 257;
      int base = (n * 5 + j) << 7;
      v = (r < 128) ? emb[base + r] : (r < 256) ? ef[base + r - 128] : td[n * 5 + j];
    }
    o[i] = f2bf(v);
  }
  *(uint2*)&dst[(size_t)nr * KDP + c0] = *(const uint2*)o;
}

// ---------------------------------------------------------------------------
// Unified bf16 MFMA GEMM. BM=64 rows, BN=144 cols per block, 256 thr,
// 4 waves as 4Mx1N (wave: 16 rows x 144 cols, 9 MFMA/step).
// A operand DIRECT TO REGISTERS (no LDS):
//   GA=0: A bf16 row-major, 1 bf8 load/lane/step.
//   GA=1: A=[emb f32 [n][128] | td | 0], 8 f32 gather + cvt.
// W staged in LDS via global_load_lds (pre-swizzled source), double-buffered.
// nch column-halves (nch=2 splits N=288 across block pairs sharing A rows).
// OM: 0=f32 row-major, 1=bf16 row-major, 2=bf16 transposed.
// ---------------------------------------------------------------------------
template<int GA, bool RELU, int OM0, int OM1, bool DUAL>
__global__ __launch_bounds__(256) void gmm_k(
    int nK, int Kw, int nch,
    const void* __restrict__ A, int ast,
    const float* __restrict__ g1, const float* __restrict__ g2,
    const u16* __restrict__ Wb,
    const float* __restrict__ b0, void* __restrict__ out0, int ost0, int N0,
    const float* __restrict__ b1, void* __restrict__ out1, int ost1,
    float scale)
{
  __shared__ u16 Ws_[2][9 * 512];
  const int t = threadIdx.x, lane = t & 63, w = t >> 6;
  const int lrow = lane & 15, lk = lane >> 4;
  const int bid = blockIdx.x;
  const int x = bid / nch, colh = bid - x * nch;
  const int n0 = x * 64;
  const int colofs = colh * 144;
  const int drow = lane >> 2, dseg = lane & 3;
  const int arow = n0 + w * 16 + lrow;

  f4_t acc[9];
#pragma unroll
  for (int ct = 0; ct < 9; ++ct) acc[ct] = (f4_t){0.f, 0.f, 0.f, 0.f};

  bf8_t afE, afO;
  float rE[8], rO[8];

  auto issueR = [&](int kst, float (&r)[8]) {    // GA==1
    const int cb = kst * 32 + lk * 8;
#pragma unroll
    for (int i = 0; i < 8; ++i) {
      int c = cb + i;
      uintptr_t pa = (uintptr_t)((const float*)A + (arow << 7) + c);
      uintptr_t pt = (uintptr_t)(g2 ? (g2 + arow) : (const float*)A);
      uintptr_t sel = (c < 128) ? pa : pt;
      float v = *(const float*)sel;
      r[i] = (c < 128) ? v : ((c == 128 && g2) ? v : 0.f);
    }
  };
  auto cvt8 = [&](const float (&r)[8]) -> bf8_t {
    union { bf8_t v; u32 u[4]; } xx;
#pragma unroll
    for (int i = 0; i < 4; ++i) xx.u[i] = pack2(r[2 * i], r[2 * i + 1]);
    return xx.v;
  };
  auto loadAf = [&](int kst) -> bf8_t {
    return *(const bf8_t*)((const u16*)A + (size_t)arow * ast + kst * 32 + lk * 8);
  };
  auto dmaW = [&](int kst, u16* wbuf) {
    const int c0 = kst * 32;
#pragma unroll
    for (int si = 0; si < 3; ++si) {
      int s = w + si * 4;            // wave-uniform
      if (s < 9) {
        int rr = colofs + s * 16 + drow;
        int sseg = (dseg ^ (rr >> 1)) & 3;
        gload16(&Wb[(size_t)rr * Kw + c0 + sseg * 8], wbuf + s * 512);
      }
    }
  };
  auto compute = [&](bf8_t af, const u16* wsb) {
#pragma unroll
    for (int ct = 0; ct < 9; ++ct) {
      bf8_t bf = *(const bf8_t*)&wsb[swz8(ct * 16 + lrow, lk)];
      acc[ct] = MFMA16(af, bf, acc[ct]);
    }
  };

  // prologue: tile 0
  if (GA == 0) afE = loadAf(0); else issueR(0, rE);
  dmaW(0, Ws_[0]);
  WAIT_VM0();
  if (GA != 0) afE = cvt8(rE);
  __builtin_amdgcn_s_barrier();

  int cur = 0, k = 0;
  while (true) {
    // even-slot step (uses afE)
    if (k + 1 < nK) {
      if (GA == 0) afO = loadAf(k + 1); else issueR(k + 1, rO);
      dmaW(k + 1, Ws_[cur ^ 1]);
    }
    compute(afE, Ws_[cur]);
    if (k + 1 >= nK) break;
    WAIT_VM0();
    if (GA != 0) afO = cvt8(rO);
    __builtin_amdgcn_s_barrier();
    cur ^= 1; ++k;
    // odd-slot step (uses afO)
    if (k + 1 < nK) {
      if (GA == 0) afE = loadAf(k + 1); else issueR(k + 1, rE);
      dmaW(k + 1, Ws_[cur ^ 1]);
    }
    compute(afO, Ws_[cur]);
    if (k + 1 >= nK) break;
    WAIT_VM0();
    if (GA != 0) afE = cvt8(rE);
    __builtin_amdgcn_s_barrier();
    cur ^= 1; ++k;
  }

  // epilogue
#pragma unroll
  for (int ct = 0; ct < 9; ++ct) {
    const int col = colofs + ct * 16 + lrow;
#pragma unroll
    for (int r = 0; r < 4; ++r) {
      const int n = n0 + w * 16 + lk * 4 + r;
      float v = acc[ct][r];
      if (col < N0) {
        v = (v + b0[col]) * scale;
        if (RELU) v = fmaxf(v, 0.f);
        if (OM0 == 0)      ((float*)out0)[(size_t)n * ost0 + col] = v;
        else if (OM0 == 1) ((u16*)out0)[(size_t)n * ost0 + col] = f2bf(v);
        else               ((u16*)out0)[(size_t)col * ost0 + n] = f2bf(v);
      } else if (DUAL) {
        int o = col - N0;
        if (o < 129) {
          v = (v + b1[o]) * scale;
          if (RELU) v = fmaxf(v, 0.f);
          if (OM1 == 0)      ((float*)out1)[(size_t)n * ost1 + o] = v;
          else if (OM1 == 1) ((u16*)out1)[(size_t)n * ost1 + o] = f2bf(v);
          else               ((u16*)out1)[(size_t)o * ost1 + n] = f2bf(v);
        }
      }
    }
  }
}

// ---------------------------------------------------------------------------
// emb pack: f32 [rows][128] -> bf16 into dst cols 129..256 (stride 288)
// ---------------------------------------------------------------------------
__global__ __launch_bounds__(256) void embpack_k(
    const float* __restrict__ src, u16* __restrict__ dst, int rows)
{
  int idx = blockIdx.x * 256 + threadIdx.x;
  if (idx >= rows * 128) return;
  int n = idx >> 7, c = idx & 127;
  dst[(size_t)n * 288 + 129 + c] = f2bf(src[idx]);
}

// ---------------------------------------------------------------------------
// i=0 attention: per batch b, 5 queries x 5 keys, dim 129.
// ---------------------------------------------------------------------------
__global__ __launch_bounds__(256) void attn0_k(
    const float* __restrict__ qp, const float* __restrict__ kp,
    const float* __restrict__ vp, u16* __restrict__ o0b)
{
  __shared__ float qs[4][5][SQ_], ks[4][5][SQ_], vs[4][5][SQ_];
  __shared__ float ps[4][5][8];
  const int t = threadIdx.x;
  const int bbase = blockIdx.x * 4;
  for (int idx = t; idx < 4 * 5 * SQ_; idx += 256) {
    int bl = idx / (5 * SQ_);
    int rem = idx - bl * 5 * SQ_;
    int row = rem / SQ_;
    int d = rem - row * SQ_;
    int n = (bbase + bl) * 5 + row;
    float qv = 0.f, kv = 0.f, vv = 0.f;
    if (d < QD_) { qv = qp[n * SQ_ + d]; kv = kp[n * SQ_ + d]; vv = vp[n * SQ_ + d]; }
    qs[bl][row][d] = qv; ks[bl][row][d] = kv; vs[bl][row][d] = vv;
  }
  __syncthreads();
  const int w = t >> 6, lane = t & 63;
  if (lane < 25) {
    int qq = lane / 5, kk = lane - (lane / 5) * 5;
    float s = 0.f;
    for (int c = 0; c < QD_; ++c) s += qs[w][qq][c] * ks[w][kk][c];
    ps[w][qq][kk] = s;
  }
  __syncthreads();
  if (lane < 5) {
    float m = -1e30f;
#pragma unroll
    for (int k = 0; k < 5; ++k) m = fmaxf(m, ps[w][lane][k]);
    float l = 0.f; float e[5];
#pragma unroll
    for (int k = 0; k < 5; ++k) { e[k] = __expf(ps[w][lane][k] - m); l += e[k]; }
    float inv = 1.f / l;
#pragma unroll
    for (int k = 0; k < 5; ++k) ps[w][lane][k] = e[k] * inv;
  }
  __syncthreads();
  for (int d = lane; d < 160; d += 64) {
#pragma unroll
    for (int qq = 0; qq < 5; ++qq) {
      float o = 0.f;
      if (d < QD_) {
#pragma unroll
        for (int k = 0; k < 5; ++k) o += ps[w][qq][k] * vs[w][k][d];
      }
      o0b[(size_t)((bbase + w) * 5 + qq) * 160 + d] = f2bf(o);
    }
  }
}

// ---------------------------------------------------------------------------
// i=1 MFMA flash attention (unchanged).
// ---------------------------------------------------------------------------
#define KSS 168
#define VSS 72
#define PSS 72
#define NSPLIT 4
__global__ __launch_bounds__(256) void flashm_k(
    const u16* __restrict__ qp, const u16* __restrict__ kp,
    const u16* __restrict__ vpT, float* __restrict__ oacc,
    float* __restrict__ marr, float* __restrict__ larr)
{
  __shared__ u16 ks[64 * KSS];
  __shared__ u16 vsT[VPAD * VSS];
  __shared__ u16 ps[64 * PSS];
  const int t = threadIdx.x;
  const int split = blockIdx.x & (NSPLIT - 1);
  const int q0 = (blockIdx.x >> 2) * 64;
  const int w = t >> 6, lane = t & 63;
  const int lrow = lane & 15, lk = lane >> 4;

  bf8_t qf[5];
  {
    const u16* qrow = qp + (size_t)(q0 + w * 16 + lrow) * QPAD;
#pragma unroll
    for (int kst = 0; kst < 5; ++kst)
      qf[kst] = *(const bf8_t*)(qrow + kst * 32 + lk * 8);
  }

  f4_t acc[9];
#pragma unroll
  for (int ct = 0; ct < 9; ++ct) acc[ct] = (f4_t){0.f, 0.f, 0.f, 0.f};
  float m_[4] = {-1e30f, -1e30f, -1e30f, -1e30f};
  float l_[4] = {0.f, 0.f, 0.f, 0.f};

  const int kbase = split * (B_ / NSPLIT);
  for (int tile = 0; tile < (B_ / NSPLIT) / 64; ++tile) {
    const int k0 = kbase + tile * 64;
    __syncthreads();
    for (int e = t; e < 64 * 20; e += 256) {
      int r = e / 20, c = e - r * 20;
      *(uint4*)&ks[r * KSS + c * 8] = *(const uint4*)(kp + (size_t)(k0 + r) * QPAD + c * 8);
    }
    for (int e = t; e < VPAD * 8; e += 256) {
      int r = e >> 3, c = e & 7;
      *(uint4*)&vsT[r * VSS + c * 8] = *(const uint4*)(vpT + (size_t)r * B_ + k0 + c * 8);
    }
    __syncthreads();

    f4_t s[4];
#pragma unroll
    for (int ct = 0; ct < 4; ++ct) s[ct] = (f4_t){0.f, 0.f, 0.f, 0.f};
#pragma unroll
    for (int kst = 0; kst < 5; ++kst) {
#pragma unroll
      for (int ct = 0; ct < 4; ++ct) {
        bf8_t b = *(const bf8_t*)&ks[(ct * 16 + lrow) * KSS + kst * 32 + lk * 8];
        s[ct] = MFMA16(qf[kst], b, s[ct]);
      }
    }

    float pm[4];
#pragma unroll
    for (int r = 0; r < 4; ++r) {
      pm[r] = fmaxf(fmaxf(s[0][r], s[1][r]), fmaxf(s[2][r], s[3][r]));
#pragma unroll
      for (int mk = 1; mk <= 8; mk <<= 1) pm[r] = fmaxf(pm[r], __shfl_xor(pm[r], mk));
    }
    float cf[4], rs[4];
#pragma unroll
    for (int r = 0; r < 4; ++r) {
      float mn = fmaxf(m_[r], pm[r]);
      cf[r] = __expf(m_[r] - mn);
      m_[r] = mn;
      rs[r] = 0.f;
    }
#pragma unroll
    for (int ct = 0; ct < 4; ++ct) {
#pragma unroll
      for (int r = 0; r < 4; ++r) {
        float p = __expf(s[ct][r] - m_[r]);
        ps[(w * 16 + lk * 4 + r) * PSS + ct * 16 + lrow] = f2bf(p);
        rs[r] += p;
      }
    }
#pragma unroll
    for (int r = 0; r < 4; ++r) {
#pragma unroll
      for (int mk = 1; mk <= 8; mk <<= 1) rs[r] += __shfl_xor(rs[r], mk);
      l_[r] = l_[r] * cf[r] + rs[r];
    }
#pragma unroll
    for (int ct = 0; ct < 9; ++ct) {
#pragma unroll
      for (int r = 0; r < 4; ++r) acc[ct][r] *= cf[r];
    }
    __syncthreads();

#pragma unroll
    for (int kst = 0; kst < 2; ++kst) {
      bf8_t a = *(const bf8_t*)&ps[(w * 16 + lrow) * PSS + kst * 32 + lk * 8];
#pragma unroll
      for (int ct = 0; ct < 9; ++ct) {
        bf8_t b = *(const bf8_t*)&vsT[(ct * 16 + lrow) * VSS + kst * 32 + lk * 8];
        acc[ct] = MFMA16(a, b, acc[ct]);
      }
    }
  }

#pragma unroll
  for (int ct = 0; ct < 9; ++ct) {
    const int col = ct * 16 + lrow;
    if (col < SQ_) {
#pragma unroll
      for (int r = 0; r < 4; ++r)
        oacc[((size_t)split * B_ + q0 + w * 16 + lk * 4 + r) * SQ_ + col] = acc[ct][r];
    }
  }
  if (lrow == 0) {
#pragma unroll
    for (int r = 0; r < 4; ++r) {
      size_t i = (size_t)split * B_ + q0 + w * 16 + lk * 4 + r;
      marr[i] = m_[r];
      larr[i] = l_[r];
    }
  }
}

// ---------------------------------------------------------------------------
// combine splits -> o1b bf16 [8192][160] (pads zeroed)
// ---------------------------------------------------------------------------
__global__ __launch_bounds__(256) void combine_k(
    const float* __restrict__ oacc, const float* __restrict__ marr,
    const float* __restrict__ larr, u16* __restrict__ o1b)
{
  int idx = blockIdx.x * 256 + threadIdx.x;
  if (idx >= B_ * 160) return;
  int n = idx / 160, d = idx - n * 160;
  float v = 0.f;
  if (d < QD_) {
    float m = -1e30f;
#pragma unroll
    for (int s = 0; s < NSPLIT; ++s) m = fmaxf(m, marr[s * B_ + n]);
    float l = 0.f, o = 0.f;
#pragma unroll
    for (int s = 0; s < NSPLIT; ++s) {
      float e = __expf(marr[s * B_ + n] - m);
      l += larr[s * B_ + n] * e;
      o += oacc[((size_t)s * B_ + n) * SQ_ + d] * e;
    }
    v = o / l;
  }
  o1b[idx] = f2bf(v);
}

// ---------------------------------------------------------------------------
extern "C" void kernel_launch(void* const* d_in, const int* in_sizes, int n_in,
                              void* d_out, int out_size, void* d_ws, size_t ws_size,
                              hipStream_t stream)
{
  const float* emb0 = (const float*)d_in[0];
  const float* ef0  = (const float*)d_in[1];
  const float* td0  = (const float*)d_in[2];
  const float* emb1 = (const float*)d_in[3];
  const float* ef1  = (const float*)d_in[4];
  const float* td1  = (const float*)d_in[5];
  const float* emb2 = (const float*)d_in[6];
  const float* Wq = (const float*)d_in[7];  const float* bq = (const float*)d_in[8];
  const float* Wk = (const float*)d_in[9];  const float* bk = (const float*)d_in[10];
  const float* Wv = (const float*)d_in[11]; const float* bv = (const float*)d_in[12];
  const float* Wo = (const float*)d_in[13]; const float* bo = (const float*)d_in[14];
  const float* W1 = (const float*)d_in[15]; const float* b1 = (const float*)d_in[16];
  const float* W2 = (const float*)d_in[17]; const float* b2 = (const float*)d_in[18];
  float* out = (float*)d_out;

  char* ws = (char*)d_ws;
  // weights bf16 @0
  u16* wb   = (u16*)ws;
  u16* wkv  = wb;
  u16* wq_b = wb + 377856;
  u16* wo_b = wb + 400896;
  u16* w1_b = wb + 423936;
  u16* w2_b = wb + 465408;
  // i=0
  float* kp0 = (float*)(ws + 1048576);     // [40960][132] f32
  float* vp0 = (float*)(ws + 22675456);    // [40960][132] f32
  u16*   nfp = (u16*)(ws + 44302336);      // [20480][1312] bf16 (row-half pack)
  float* qp0 = (float*)(ws + 44302336);    // overlays nfp after kv0
  u16*   o0b = (u16*)(ws + 65929216);      // [40960][160] bf16
  u16*   cat0= (u16*)(ws + 1048576);       // [40960][288] bf16 (overlays kp0/vp0)
  u16*   h0  = (u16*)(ws + 24641536);      // [40960][128] bf16
  // i=1 (live only after i=0 fully drained)
  u16*   nf1p = (u16*)(ws + 1048576);      // [8192][1312] bf16
  u16*   qp1b = (u16*)(ws + 22675456);     // [8192][160]
  u16*   kp1b = (u16*)(ws + 25296896);     // [8192][160]
  u16*   vp1T = (u16*)(ws + 27918336);     // [144][8192]
  u16*   o1b  = (u16*)(ws + 30277632);     // [8192][160]
  float* marr = (float*)(ws + 32899072);
  float* larr = (float*)(ws + 33030144);
  u16*   cat1 = (u16*)(ws + 33161216);     // [8192][288]
  u16*   h1   = (u16*)(ws + 37879808);     // [8192][128]
  float* oacc = (float*)(ws + 79036416);   // [4][8192][132]

  const float scale = 0.08804509063256238f;  // 1/sqrt(129)
  const int HROWS = 20480;                   // i=0 row-half

  convw_k<<<1890, 256, 0, stream>>>(Wq, Wk, Wv, Wo, W1, W2, wb);

  // ---- i = 0 -------------------------------------------------------------
  // KV projection in two row-halves: pack nf -> bf16, then pure-bf16 GEMM.
  for (int h = 0; h < 2; ++h) {
    packnf_k<<<(HROWS * 328 + 255) / 256, 256, 0, stream>>>(
        emb0, ef0, td0, nfp, h * HROWS, HROWS);
    gmm_k<0, false, 0, 0, true><<<(HROWS / 64) * 2, 256, 0, stream>>>(
        41, KDP, 2, nfp, KDP, nullptr, nullptr, wkv,
        bk, kp0 + (size_t)h * HROWS * SQ_, SQ_, QD_,
        bv, vp0 + (size_t)h * HROWS * SQ_, SQ_, 1.f);
  }
  // qp0 (f32)
  gmm_k<1, false, 0, 0, false><<<640, 256, 0, stream>>>(
      5, 160, 1, emb1, 0, nullptr, td1, wq_b,
      bq, qp0, SQ_, QD_, nullptr, nullptr, 0, scale);
  attn0_k<<<B_ / 4, 256, 0, stream>>>(qp0, kp0, vp0, o0b);
  hipMemsetAsync(cat0, 0, 23592960, stream);
  embpack_k<<<(BK_ * 128 + 255) / 256, 256, 0, stream>>>(emb1, cat0, BK_);
  // Wo -> cat0 cols 0..128 (bf16)
  gmm_k<0, false, 1, 0, false><<<640, 256, 0, stream>>>(
      5, 160, 1, o0b, 160, nullptr, nullptr, wo_b,
      bo, cat0, 288, QD_, nullptr, nullptr, 0, 1.f);
  // W1 relu -> h0 (bf16)
  gmm_k<0, true, 1, 0, false><<<640, 256, 0, stream>>>(
      9, 288, 1, cat0, 288, nullptr, nullptr, w1_b,
      b1, h0, 128, 128, nullptr, nullptr, 0, 1.f);
  // W2 -> out (f32)
  gmm_k<0, false, 0, 0, false><<<640, 256, 0, stream>>>(
      4, 128, 1, h0, 128, nullptr, nullptr, w2_b,
      b2, out, 128, 128, nullptr, nullptr, 0, 1.f);

  // ---- i = 1 -------------------------------------------------------------
  packnf_k<<<(B_ * 328 + 255) / 256, 256, 0, stream>>>(
      emb1, ef1, td1, nf1p, 0, B_);
  hipMemsetAsync(qp1b, 0, 2621440, stream);
  hipMemsetAsync(kp1b, 0, 2621440, stream);
  hipMemsetAsync(vp1T, 0, 2359296, stream);
  gmm_k<0, false, 1, 2, true><<<(B_ / 64) * 2, 256, 0, stream>>>(
      41, KDP, 2, nf1p, KDP, nullptr, nullptr, wkv,
      bk, kp1b, QPAD, QD_, bv, vp1T, B_, 1.f);
  gmm_k<1, false, 1, 0, false><<<128, 256, 0, stream>>>(
      5, 160, 1, emb2, 0, nullptr, nullptr, wq_b,
      bq, qp1b, QPAD, QD_, nullptr, nullptr, 0, scale);
  flashm_k<<<(B_ / 64) * NSPLIT, 256, 0, stream>>>(qp1b, kp1b, vp1T, oacc, marr, larr);
  combine_k<<<(B_ * 160 + 255) / 256, 256, 0, stream>>>(oacc, marr, larr, o1b);
  hipMemsetAsync(cat1, 0, 4718592, stream);
  embpack_k<<<(B_ * 128 + 255) / 256, 256, 0, stream>>>(emb2, cat1, B_);
  gmm_k<0, false, 1, 0, false><<<128, 256, 0, stream>>>(
      5, 160, 1, o1b, 160, nullptr, nullptr, wo_b,
      bo, cat1, 288, QD_, nullptr, nullptr, 0, 1.f);
  gmm_k<0, true, 1, 0, false><<<128, 256, 0, stream>>>(
      9, 288, 1, cat1, 288, nullptr, nullptr, w1_b,
      b1, h1, 128, 128, nullptr, nullptr, 0, 1.f);
  gmm_k<0, false, 0, 0, false><<<128, 256, 0, stream>>>(
      4, 128, 1, h1, 128, nullptr, nullptr, w2_b,
      b2, out + (size_t)BK_ * D_, 128, 128, nullptr, nullptr, 0, 1.f);
}

// Round 10
// 451.371 us; speedup vs baseline: 1.4663x; 1.1265x over previous
//
#include <hip/hip_runtime.h>

#define B_   8192
#define K_   5
#define D_   128
#define QD_  129
#define KD_  1285
#define SQ_  132      // padded fp32 row stride
#define BK_  40960    // B_*K_
#define QPAD 160      // bf16 k-dim padding (5 x 32)
#define VPAD 144      // bf16 out-dim padding (9 x 16)
#define KDP  1312     // KD_ padded to 41*32

typedef unsigned short u16;
typedef unsigned int   u32;
typedef __attribute__((ext_vector_type(8))) short bf8_t;
typedef __attribute__((ext_vector_type(4))) float f4_t;
typedef __attribute__((address_space(3))) u32 lds_u32;
typedef __attribute__((address_space(1))) const u32 glob_u32;

#define MFMA16(a, b, c) __builtin_amdgcn_mfma_f32_16x16x32_bf16(a, b, c, 0, 0, 0)

__device__ __forceinline__ u16 f2bf(float x) {
  u32 u = __float_as_uint(x);
  u = (u + 0x7fffu + ((u >> 16) & 1u)) >> 16;
  return (u16)u;
}
__device__ __forceinline__ u32 pack2(float a, float b) {
  return (u32)f2bf(a) | ((u32)f2bf(b) << 16);
}
// LDS layout: row stride 32 u16 (64B), 8-u16 sub-blocks XOR-swizzled by row.
__device__ __forceinline__ int swz8(int row, int seg) {
  return (row << 5) + (((seg ^ (row >> 1)) & 3) << 3);
}
__device__ __forceinline__ void gload16(const u16* src, u16* ldsdst) {
  __builtin_amdgcn_global_load_lds((glob_u32*)src, (lds_u32*)ldsdst, 16, 0, 0);
}
#define WAIT_VM0() asm volatile("s_waitcnt vmcnt(0)" ::: "memory")
#define WAIT_VM3() asm volatile("s_waitcnt vmcnt(3)" ::: "memory")
#define WAIT_VM6() asm volatile("s_waitcnt vmcnt(6)" ::: "memory")
#define WAIT_LGKM0() asm volatile("s_waitcnt lgkmcnt(0)" ::: "memory")

// ---------------------------------------------------------------------------
// One-time weight conversion fp32 -> bf16 with zero padding.
//   wkv [288][1312] @0        rows 0-128 Wk, 129-257 Wv
//   wq  [144][160]  @377856
//   wo  [144][160]  @400896
//   w1  [144][288]  @423936
//   w2  [144][128]  @465408
// ---------------------------------------------------------------------------
__global__ __launch_bounds__(256) void convw_k(
    const float* __restrict__ Wq, const float* __restrict__ Wk,
    const float* __restrict__ Wv, const float* __restrict__ Wo,
    const float* __restrict__ W1, const float* __restrict__ W2,
    u16* __restrict__ wb)
{
  int idx = blockIdx.x * 256 + threadIdx.x;
  if (idx < 377856) {
    int r = idx / KDP, c = idx - r * KDP;
    float v = 0.f;
    if (c < KD_) {
      if (r < 129) v = Wk[r * KD_ + c];
      else if (r < 258) v = Wv[(r - 129) * KD_ + c];
    }
    wb[idx] = f2bf(v);
    return;
  }
  int i2 = idx - 377856;
  if (i2 < 23040) {
    int r = i2 / 160, c = i2 - r * 160;
    wb[idx] = f2bf((r < 129 && c < 129) ? Wq[r * 129 + c] : 0.f);
    return;
  }
  i2 -= 23040;
  if (i2 < 23040) {
    int r = i2 / 160, c = i2 - r * 160;
    wb[idx] = f2bf((r < 129 && c < 129) ? Wo[r * 129 + c] : 0.f);
    return;
  }
  i2 -= 23040;
  if (i2 < 41472) {
    int r = i2 / 288, c = i2 - r * 288;
    wb[idx] = f2bf((r < 128 && c < 257) ? W1[r * 257 + c] : 0.f);
    return;
  }
  i2 -= 41472;
  if (i2 < 18432) {
    int r = i2 / 128, c = i2 - r * 128;
    wb[idx] = f2bf(r < 128 ? W2[r * 128 + c] : 0.f);
  }
}

// ---------------------------------------------------------------------------
// nf pack: gather [emb|ef|td]x5 fp32 -> bf16 [rows][KDP], zero-padded.
// ---------------------------------------------------------------------------
__global__ __launch_bounds__(256) void packnf_k(
    const float* __restrict__ emb, const float* __restrict__ ef,
    const float* __restrict__ td, u16* __restrict__ dst, int nofs, int rows)
{
  int idx = blockIdx.x * 256 + threadIdx.x;
  if (idx >= rows * 328) return;
  int nr = idx / 328, q = idx - nr * 328;
  const int n = nofs + nr;
  const int c0 = q * 4;
  u16 o[4];
#pragma unroll
  for (int i = 0; i < 4; ++i) {
    int c = c0 + i;
    float v = 0.f;
    if (c < KD_) {
      int j = c / 257, r = c - j * 257;
      int base = (n * 5 + j) << 7;
      v = (r < 128) ? emb[base + r] : (r < 256) ? ef[base + r - 128] : td[n * 5 + j];
    }
    o[i] = f2bf(v);
  }
  *(uint2*)&dst[(size_t)nr * KDP + c0] = *(const uint2*)o;
}

// ---------------------------------------------------------------------------
// Unified bf16 MFMA GEMM (unchanged from round 9).
// ---------------------------------------------------------------------------
template<int GA, bool RELU, int OM0, int OM1, bool DUAL>
__global__ __launch_bounds__(256) void gmm_k(
    int nK, int Kw, int nch,
    const void* __restrict__ A, int ast,
    const float* __restrict__ g1, const float* __restrict__ g2,
    const u16* __restrict__ Wb,
    const float* __restrict__ b0, void* __restrict__ out0, int ost0, int N0,
    const float* __restrict__ b1, void* __restrict__ out1, int ost1,
    float scale)
{
  __shared__ u16 Ws_[2][9 * 512];
  const int t = threadIdx.x, lane = t & 63, w = t >> 6;
  const int lrow = lane & 15, lk = lane >> 4;
  const int bid = blockIdx.x;
  const int x = bid / nch, colh = bid - x * nch;
  const int n0 = x * 64;
  const int colofs = colh * 144;
  const int drow = lane >> 2, dseg = lane & 3;
  const int arow = n0 + w * 16 + lrow;

  f4_t acc[9];
#pragma unroll
  for (int ct = 0; ct < 9; ++ct) acc[ct] = (f4_t){0.f, 0.f, 0.f, 0.f};

  bf8_t afE, afO;
  float rE[8], rO[8];

  auto issueR = [&](int kst, float (&r)[8]) {    // GA==1
    const int cb = kst * 32 + lk * 8;
#pragma unroll
    for (int i = 0; i < 8; ++i) {
      int c = cb + i;
      uintptr_t pa = (uintptr_t)((const float*)A + (arow << 7) + c);
      uintptr_t pt = (uintptr_t)(g2 ? (g2 + arow) : (const float*)A);
      uintptr_t sel = (c < 128) ? pa : pt;
      float v = *(const float*)sel;
      r[i] = (c < 128) ? v : ((c == 128 && g2) ? v : 0.f);
    }
  };
  auto cvt8 = [&](const float (&r)[8]) -> bf8_t {
    union { bf8_t v; u32 u[4]; } xx;
#pragma unroll
    for (int i = 0; i < 4; ++i) xx.u[i] = pack2(r[2 * i], r[2 * i + 1]);
    return xx.v;
  };
  auto loadAf = [&](int kst) -> bf8_t {
    return *(const bf8_t*)((const u16*)A + (size_t)arow * ast + kst * 32 + lk * 8);
  };
  auto dmaW = [&](int kst, u16* wbuf) {
    const int c0 = kst * 32;
#pragma unroll
    for (int si = 0; si < 3; ++si) {
      int s = w + si * 4;            // wave-uniform
      if (s < 9) {
        int rr = colofs + s * 16 + drow;
        int sseg = (dseg ^ (rr >> 1)) & 3;
        gload16(&Wb[(size_t)rr * Kw + c0 + sseg * 8], wbuf + s * 512);
      }
    }
  };
  auto compute = [&](bf8_t af, const u16* wsb) {
#pragma unroll
    for (int ct = 0; ct < 9; ++ct) {
      bf8_t bf = *(const bf8_t*)&wsb[swz8(ct * 16 + lrow, lk)];
      acc[ct] = MFMA16(af, bf, acc[ct]);
    }
  };

  // prologue: tile 0
  if (GA == 0) afE = loadAf(0); else issueR(0, rE);
  dmaW(0, Ws_[0]);
  WAIT_VM0();
  if (GA != 0) afE = cvt8(rE);
  __builtin_amdgcn_s_barrier();

  int cur = 0, k = 0;
  while (true) {
    if (k + 1 < nK) {
      if (GA == 0) afO = loadAf(k + 1); else issueR(k + 1, rO);
      dmaW(k + 1, Ws_[cur ^ 1]);
    }
    compute(afE, Ws_[cur]);
    if (k + 1 >= nK) break;
    WAIT_VM0();
    if (GA != 0) afO = cvt8(rO);
    __builtin_amdgcn_s_barrier();
    cur ^= 1; ++k;
    if (k + 1 < nK) {
      if (GA == 0) afE = loadAf(k + 1); else issueR(k + 1, rE);
      dmaW(k + 1, Ws_[cur ^ 1]);
    }
    compute(afO, Ws_[cur]);
    if (k + 1 >= nK) break;
    WAIT_VM0();
    if (GA != 0) afE = cvt8(rE);
    __builtin_amdgcn_s_barrier();
    cur ^= 1; ++k;
  }

  // epilogue
#pragma unroll
  for (int ct = 0; ct < 9; ++ct) {
    const int col = colofs + ct * 16 + lrow;
#pragma unroll
    for (int r = 0; r < 4; ++r) {
      const int n = n0 + w * 16 + lk * 4 + r;
      float v = acc[ct][r];
      if (col < N0) {
        v = (v + b0[col]) * scale;
        if (RELU) v = fmaxf(v, 0.f);
        if (OM0 == 0)      ((float*)out0)[(size_t)n * ost0 + col] = v;
        else if (OM0 == 1) ((u16*)out0)[(size_t)n * ost0 + col] = f2bf(v);
        else               ((u16*)out0)[(size_t)col * ost0 + n] = f2bf(v);
      } else if (DUAL) {
        int o = col - N0;
        if (o < 129) {
          v = (v + b1[o]) * scale;
          if (RELU) v = fmaxf(v, 0.f);
          if (OM1 == 0)      ((float*)out1)[(size_t)n * ost1 + o] = v;
          else if (OM1 == 1) ((u16*)out1)[(size_t)n * ost1 + o] = f2bf(v);
          else               ((u16*)out1)[(size_t)o * ost1 + n] = f2bf(v);
        }
      }
    }
  }
}

// ---------------------------------------------------------------------------
// emb pack: f32 [rows][128] -> bf16 into dst cols 129..256 (stride 288)
// ---------------------------------------------------------------------------
__global__ __launch_bounds__(256) void embpack_k(
    const float* __restrict__ src, u16* __restrict__ dst, int rows)
{
  int idx = blockIdx.x * 256 + threadIdx.x;
  if (idx >= rows * 128) return;
  int n = idx >> 7, c = idx & 127;
  dst[(size_t)n * 288 + 129 + c] = f2bf(src[idx]);
}

// ---------------------------------------------------------------------------
// i=0 attention: per batch b, 5 queries x 5 keys, dim 129.
// ---------------------------------------------------------------------------
__global__ __launch_bounds__(256) void attn0_k(
    const float* __restrict__ qp, const float* __restrict__ kp,
    const float* __restrict__ vp, u16* __restrict__ o0b)
{
  __shared__ float qs[4][5][SQ_], ks[4][5][SQ_], vs[4][5][SQ_];
  __shared__ float ps[4][5][8];
  const int t = threadIdx.x;
  const int bbase = blockIdx.x * 4;
  for (int idx = t; idx < 4 * 5 * SQ_; idx += 256) {
    int bl = idx / (5 * SQ_);
    int rem = idx - bl * 5 * SQ_;
    int row = rem / SQ_;
    int d = rem - row * SQ_;
    int n = (bbase + bl) * 5 + row;
    float qv = 0.f, kv = 0.f, vv = 0.f;
    if (d < QD_) { qv = qp[n * SQ_ + d]; kv = kp[n * SQ_ + d]; vv = vp[n * SQ_ + d]; }
    qs[bl][row][d] = qv; ks[bl][row][d] = kv; vs[bl][row][d] = vv;
  }
  __syncthreads();
  const int w = t >> 6, lane = t & 63;
  if (lane < 25) {
    int qq = lane / 5, kk = lane - (lane / 5) * 5;
    float s = 0.f;
    for (int c = 0; c < QD_; ++c) s += qs[w][qq][c] * ks[w][kk][c];
    ps[w][qq][kk] = s;
  }
  __syncthreads();
  if (lane < 5) {
    float m = -1e30f;
#pragma unroll
    for (int k = 0; k < 5; ++k) m = fmaxf(m, ps[w][lane][k]);
    float l = 0.f; float e[5];
#pragma unroll
    for (int k = 0; k < 5; ++k) { e[k] = __expf(ps[w][lane][k] - m); l += e[k]; }
    float inv = 1.f / l;
#pragma unroll
    for (int k = 0; k < 5; ++k) ps[w][lane][k] = e[k] * inv;
  }
  __syncthreads();
  for (int d = lane; d < 160; d += 64) {
#pragma unroll
    for (int qq = 0; qq < 5; ++qq) {
      float o = 0.f;
      if (d < QD_) {
#pragma unroll
        for (int k = 0; k < 5; ++k) o += ps[w][qq][k] * vs[w][k][d];
      }
      o0b[(size_t)((bbase + w) * 5 + qq) * 160 + d] = f2bf(o);
    }
  }
}

// ---------------------------------------------------------------------------
// i=1 MFMA flash attention, rebuilt on swz8 subtiles + global_load_lds DMA
// + counted-vmcnt pipeline. QB=128 q-rows (8 waves), KVB=64-key tiles,
// NSPLIT=8 K-splits. LDS: K dbuf 2x20KB, V 18KB, P 16KB = 74KB.
// ---------------------------------------------------------------------------
#define QB   128
#define KVB  64
#define NSPLIT 8
#define NT   ((B_ / NSPLIT) / KVB)    // 16
__global__ __launch_bounds__(512, 4) void flashm_k(
    const u16* __restrict__ qp, const u16* __restrict__ kp,
    const u16* __restrict__ vpT, float* __restrict__ oacc,
    float* __restrict__ marr, float* __restrict__ larr)
{
  __shared__ u16 Ks[2][5 * 2048];   // [buf][kst][64][32] swz8
  __shared__ u16 Vs[2 * 4608];      // [kst2][144][32] swz8
  __shared__ u16 Ps[2 * 4096];      // [kst2][128][32] swz8
  const int t = threadIdx.x, lane = t & 63, w = t >> 6;
  const int lrow = lane & 15, lk = lane >> 4;
  const int split = blockIdx.x & (NSPLIT - 1);
  const int q0 = (blockIdx.x >> 3) * QB;
  const int drow = lane >> 2, dseg = lane & 3;
  const int kbase = split * (B_ / NSPLIT);

  // 24-seg-padded DMA: every wave exactly 3 K + 3 V per tile (dummies rewrite
  // real segs with identical data -> benign).
  auto dmaK = [&](int k0, u16* kb) {
#pragma unroll
    for (int si = 0; si < 3; ++si) {
      int s = w + si * 8;
      if (s >= 20) s -= 20;
      int kst = s >> 2, rg = s & 3;
      int r = rg * 16 + drow;
      int sseg = (dseg ^ (r >> 1)) & 3;
      gload16(&kp[(size_t)(k0 + r) * QPAD + kst * 32 + sseg * 8],
              kb + kst * 2048 + rg * 512);
    }
  };
  auto dmaV = [&](int k0) {
#pragma unroll
    for (int si = 0; si < 3; ++si) {
      int s = w + si * 8;
      if (s >= 18) s -= 18;
      int kst = (s >= 9) ? 1 : 0;
      int rg = s - kst * 9;
      int r = rg * 16 + drow;
      int sseg = (dseg ^ (r >> 1)) & 3;
      gload16(&vpT[(size_t)r * B_ + k0 + kst * 32 + sseg * 8],
              Vs + kst * 4608 + rg * 512);
    }
  };

  // Q fragments (one-time global load)
  bf8_t qf[5];
  {
    const u16* qrow = qp + (size_t)(q0 + w * 16 + lrow) * QPAD;
#pragma unroll
    for (int kst = 0; kst < 5; ++kst)
      qf[kst] = *(const bf8_t*)(qrow + kst * 32 + lk * 8);
  }

  f4_t acc[9];
#pragma unroll
  for (int ct = 0; ct < 9; ++ct) acc[ct] = (f4_t){0.f, 0.f, 0.f, 0.f};
  float m_[4] = {-1e30f, -1e30f, -1e30f, -1e30f};
  float l_[4] = {0.f, 0.f, 0.f, 0.f};

  dmaK(kbase, Ks[0]);
  for (int tl = 0; tl < NT; ++tl) {
    const int k0 = kbase + tl * KVB;
    const int cur = tl & 1;
    dmaV(k0);
    const bool more = (tl + 1 < NT);
    if (more) dmaK(k0 + KVB, Ks[cur ^ 1]);
    if (more) { WAIT_VM6(); } else { WAIT_VM3(); }   // K(tl) landed
    __builtin_amdgcn_s_barrier();

    // QK^T: 5 ksts x 4 col-tiles
    f4_t s4[4];
#pragma unroll
    for (int ct = 0; ct < 4; ++ct) s4[ct] = (f4_t){0.f, 0.f, 0.f, 0.f};
#pragma unroll
    for (int kst = 0; kst < 5; ++kst) {
#pragma unroll
      for (int ct = 0; ct < 4; ++ct) {
        bf8_t b = *(const bf8_t*)&Ks[cur][kst * 2048 + swz8(ct * 16 + lrow, lk)];
        s4[ct] = MFMA16(qf[kst], b, s4[ct]);
      }
    }

    // online softmax (rows lk*4+r; 16-lane groups share rows)
    float pm[4];
#pragma unroll
    for (int r = 0; r < 4; ++r) {
      pm[r] = fmaxf(fmaxf(s4[0][r], s4[1][r]), fmaxf(s4[2][r], s4[3][r]));
#pragma unroll
      for (int mk = 1; mk <= 8; mk <<= 1) pm[r] = fmaxf(pm[r], __shfl_xor(pm[r], mk));
    }
    float cf[4], rs[4];
#pragma unroll
    for (int r = 0; r < 4; ++r) {
      float mn = fmaxf(m_[r], pm[r]);
      cf[r] = __expf(m_[r] - mn);
      m_[r] = mn;
      rs[r] = 0.f;
    }
#pragma unroll
    for (int ct = 0; ct < 4; ++ct) {
#pragma unroll
      for (int r = 0; r < 4; ++r) {
        float p = __expf(s4[ct][r] - m_[r]);
        const int q = w * 16 + lk * 4 + r;
        const int col = ((ct & 1) << 4) + lrow;
        Ps[(ct >> 1) * 4096 + (q << 5) + ((((col >> 3) ^ (q >> 1)) & 3) << 3) + (col & 7)]
            = f2bf(p);
        rs[r] += p;
      }
    }
#pragma unroll
    for (int r = 0; r < 4; ++r) {
#pragma unroll
      for (int mk = 1; mk <= 8; mk <<= 1) rs[r] += __shfl_xor(rs[r], mk);
      l_[r] = l_[r] * cf[r] + rs[r];
    }
#pragma unroll
    for (int ct = 0; ct < 9; ++ct) {
#pragma unroll
      for (int r = 0; r < 4; ++r) acc[ct][r] *= cf[r];
    }
    WAIT_LGKM0();
    __builtin_amdgcn_sched_barrier(0);

    if (more) { WAIT_VM3(); } else { WAIT_VM0(); }   // V(tl) landed
    __builtin_amdgcn_s_barrier();

    // PV: 2 ksts x 9 col-tiles
#pragma unroll
    for (int kst = 0; kst < 2; ++kst) {
      bf8_t a = *(const bf8_t*)&Ps[kst * 4096 + swz8(w * 16 + lrow, lk)];
#pragma unroll
      for (int ct = 0; ct < 9; ++ct) {
        bf8_t b = *(const bf8_t*)&Vs[kst * 4608 + swz8(ct * 16 + lrow, lk)];
        acc[ct] = MFMA16(a, b, acc[ct]);
      }
    }
    __builtin_amdgcn_s_barrier();   // Vs free for next dmaV
  }

  // store unnormalized acc + m,l
#pragma unroll
  for (int ct = 0; ct < 9; ++ct) {
    const int col = ct * 16 + lrow;
    if (col < SQ_) {
#pragma unroll
      for (int r = 0; r < 4; ++r)
        oacc[((size_t)split * B_ + q0 + w * 16 + lk * 4 + r) * SQ_ + col] = acc[ct][r];
    }
  }
  if (lrow == 0) {
#pragma unroll
    for (int r = 0; r < 4; ++r) {
      size_t i = (size_t)split * B_ + q0 + w * 16 + lk * 4 + r;
      marr[i] = m_[r];
      larr[i] = l_[r];
    }
  }
}

// ---------------------------------------------------------------------------
// combine splits -> o1b bf16 [8192][160] (pads zeroed)
// ---------------------------------------------------------------------------
__global__ __launch_bounds__(256) void combine_k(
    const float* __restrict__ oacc, const float* __restrict__ marr,
    const float* __restrict__ larr, u16* __restrict__ o1b)
{
  int idx = blockIdx.x * 256 + threadIdx.x;
  if (idx >= B_ * 160) return;
  int n = idx / 160, d = idx - n * 160;
  float v = 0.f;
  if (d < QD_) {
    float m = -1e30f;
#pragma unroll
    for (int s = 0; s < NSPLIT; ++s) m = fmaxf(m, marr[s * B_ + n]);
    float l = 0.f, o = 0.f;
#pragma unroll
    for (int s = 0; s < NSPLIT; ++s) {
      float e = __expf(marr[s * B_ + n] - m);
      l += larr[s * B_ + n] * e;
      o += oacc[((size_t)s * B_ + n) * SQ_ + d] * e;
    }
    v = o / l;
  }
  o1b[idx] = f2bf(v);
}

// ---------------------------------------------------------------------------
extern "C" void kernel_launch(void* const* d_in, const int* in_sizes, int n_in,
                              void* d_out, int out_size, void* d_ws, size_t ws_size,
                              hipStream_t stream)
{
  const float* emb0 = (const float*)d_in[0];
  const float* ef0  = (const float*)d_in[1];
  const float* td0  = (const float*)d_in[2];
  const float* emb1 = (const float*)d_in[3];
  const float* ef1  = (const float*)d_in[4];
  const float* td1  = (const float*)d_in[5];
  const float* emb2 = (const float*)d_in[6];
  const float* Wq = (const float*)d_in[7];  const float* bq = (const float*)d_in[8];
  const float* Wk = (const float*)d_in[9];  const float* bk = (const float*)d_in[10];
  const float* Wv = (const float*)d_in[11]; const float* bv = (const float*)d_in[12];
  const float* Wo = (const float*)d_in[13]; const float* bo = (const float*)d_in[14];
  const float* W1 = (const float*)d_in[15]; const float* b1 = (const float*)d_in[16];
  const float* W2 = (const float*)d_in[17]; const float* b2 = (const float*)d_in[18];
  float* out = (float*)d_out;

  char* ws = (char*)d_ws;
  // weights bf16 @0
  u16* wb   = (u16*)ws;
  u16* wkv  = wb;
  u16* wq_b = wb + 377856;
  u16* wo_b = wb + 400896;
  u16* w1_b = wb + 423936;
  u16* w2_b = wb + 465408;
  // i=0
  float* kp0 = (float*)(ws + 1048576);     // [40960][132] f32
  float* vp0 = (float*)(ws + 22675456);    // [40960][132] f32
  u16*   nfp = (u16*)(ws + 44302336);      // [20480][1312] bf16 (row-half pack)
  float* qp0 = (float*)(ws + 44302336);    // overlays nfp after kv0
  u16*   o0b = (u16*)(ws + 65929216);      // [40960][160] bf16
  u16*   cat0= (u16*)(ws + 1048576);       // [40960][288] bf16 (overlays kp0/vp0)
  u16*   h0  = (u16*)(ws + 24641536);      // [40960][128] bf16
  // i=1 (live only after i=0 fully drained)
  u16*   nf1p = (u16*)(ws + 1048576);      // [8192][1312] bf16
  u16*   qp1b = (u16*)(ws + 22675456);     // [8192][160]
  u16*   kp1b = (u16*)(ws + 25296896);
  u16*   vp1T = (u16*)(ws + 27918336);     // [144][8192]
  u16*   o1b  = (u16*)(ws + 30277632);     // [8192][160]
  float* marr = (float*)(ws + 32899072);   // [8][8192]
  float* larr = (float*)(ws + 33161216);   // [8][8192]
  u16*   cat1 = (u16*)(ws + 33423360);     // [8192][288]
  u16*   h1   = (u16*)(ws + 38141952);     // [8192][128]
  float* oacc = (float*)(ws + 40239104);   // [8][8192][132] f32 (~34.6 MB)

  const float scale = 0.08804509063256238f;  // 1/sqrt(129)
  const int HROWS = 20480;                   // i=0 row-half

  convw_k<<<1890, 256, 0, stream>>>(Wq, Wk, Wv, Wo, W1, W2, wb);

  // ---- i = 0 -------------------------------------------------------------
  for (int h = 0; h < 2; ++h) {
    packnf_k<<<(HROWS * 328 + 255) / 256, 256, 0, stream>>>(
        emb0, ef0, td0, nfp, h * HROWS, HROWS);
    gmm_k<0, false, 0, 0, true><<<(HROWS / 64) * 2, 256, 0, stream>>>(
        41, KDP, 2, nfp, KDP, nullptr, nullptr, wkv,
        bk, kp0 + (size_t)h * HROWS * SQ_, SQ_, QD_,
        bv, vp0 + (size_t)h * HROWS * SQ_, SQ_, 1.f);
  }
  gmm_k<1, false, 0, 0, false><<<640, 256, 0, stream>>>(
      5, 160, 1, emb1, 0, nullptr, td1, wq_b,
      bq, qp0, SQ_, QD_, nullptr, nullptr, 0, scale);
  attn0_k<<<B_ / 4, 256, 0, stream>>>(qp0, kp0, vp0, o0b);
  hipMemsetAsync(cat0, 0, 23592960, stream);
  embpack_k<<<(BK_ * 128 + 255) / 256, 256, 0, stream>>>(emb1, cat0, BK_);
  gmm_k<0, false, 1, 0, false><<<640, 256, 0, stream>>>(
      5, 160, 1, o0b, 160, nullptr, nullptr, wo_b,
      bo, cat0, 288, QD_, nullptr, nullptr, 0, 1.f);
  gmm_k<0, true, 1, 0, false><<<640, 256, 0, stream>>>(
      9, 288, 1, cat0, 288, nullptr, nullptr, w1_b,
      b1, h0, 128, 128, nullptr, nullptr, 0, 1.f);
  gmm_k<0, false, 0, 0, false><<<640, 256, 0, stream>>>(
      4, 128, 1, h0, 128, nullptr, nullptr, w2_b,
      b2, out, 128, 128, nullptr, nullptr, 0, 1.f);

  // ---- i = 1 -------------------------------------------------------------
  packnf_k<<<(B_ * 328 + 255) / 256, 256, 0, stream>>>(
      emb1, ef1, td1, nf1p, 0, B_);
  hipMemsetAsync(qp1b, 0, 2621440, stream);
  hipMemsetAsync(kp1b, 0, 2621440, stream);
  hipMemsetAsync(vp1T, 0, 2359296, stream);
  gmm_k<0, false, 1, 2, true><<<(B_ / 64) * 2, 256, 0, stream>>>(
      41, KDP, 2, nf1p, KDP, nullptr, nullptr, wkv,
      bk, kp1b, QPAD, QD_, bv, vp1T, B_, 1.f);
  gmm_k<1, false, 1, 0, false><<<128, 256, 0, stream>>>(
      5, 160, 1, emb2, 0, nullptr, nullptr, wq_b,
      bq, qp1b, QPAD, QD_, nullptr, nullptr, 0, scale);
  flashm_k<<<(B_ / QB) * NSPLIT, 512, 0, stream>>>(qp1b, kp1b, vp1T, oacc, marr, larr);
  combine_k<<<(B_ * 160 + 255) / 256, 256, 0, stream>>>(oacc, marr, larr, o1b);
  hipMemsetAsync(cat1, 0, 4718592, stream);
  embpack_k<<<(B_ * 128 + 255) / 256, 256, 0, stream>>>(emb2, cat1, B_);
  gmm_k<0, false, 1, 0, false><<<128, 256, 0, stream>>>(
      5, 160, 1, o1b, 160, nullptr, nullptr, wo_b,
      bo, cat1, 288, QD_, nullptr, nullptr, 0, 1.f);
  gmm_k<0, true, 1, 0, false><<<128, 256, 0, stream>>>(
      9, 288, 1, cat1, 288, nullptr, nullptr, w1_b,
      b1, h1, 128, 128, nullptr, nullptr, 0, 1.f);
  gmm_k<0, false, 0, 0, false><<<128, 256, 0, stream>>>(
      4, 128, 1, h1, 128, nullptr, nullptr, w2_b,
      b2, out + (size_t)BK_ * D_, 128, 128, nullptr, nullptr, 0, 1.f);
}